// Round 12
// baseline (4425.064 us; speedup 1.0000x reference)
//
#include <hip/hip_runtime.h>
#include <hip/hip_bf16.h>

// ZOH linear layer: K[1,8192], dim 2048.
// Y2=(0.91A)^2, ER, ER4 via bf16x3-split MFMA GEMMs (XCD-swizzled); E,E8 elementwise.
// W=inv(A+1e-3 I) f64 in-place flat blocked GJ (gj64 v6 unpivoted col-major;
// 128x128-tile f64 trailing update, XCD-swizzled) + 1 f64 IR step.
// K[91j+i] = (C*AR^j)·(A^i*Bbar): bootstrap 7 serial + 22 batched chain launches + dots.

#define DIMN 2048
#define MSTEPS 8192
#define RSPLIT 91
#define NN ((size_t)DIMN * DIMN)
#define NBLK 32
#define ALD 36   // LDS pitch (bf16) for gemm3
#define GJP 65   // gj64 panel pitch (f64)
#define TBM 128  // trailing-update tile

typedef short short8 __attribute__((ext_vector_type(8)));
typedef float f32x4 __attribute__((ext_vector_type(4)));

__device__ inline void split1(float x, unsigned short& h, unsigned short& l)
{
  __hip_bfloat16 b = __float2bfloat16(x);
  h = *reinterpret_cast<unsigned short*>(&b);
  float r = x - __bfloat162float(b);
  __hip_bfloat16 b2 = __float2bfloat16(r);
  l = *reinterpret_cast<unsigned short*>(&b2);
}

// ---------------- elementwise f32: out = c1*i1+c2*i2 + dval*I ----------------
__global__ __launch_bounds__(256)
void k_combine4(float* out,
                const float* i1, float c1, const float* i2, float c2,
                const float* i3, float c3, const float* i4, float c4,
                float dval)
{
  const int total = DIMN * DIMN;
  for (int idx = blockIdx.x * 256 + threadIdx.x; idx < total; idx += gridDim.x * 256) {
    float v = 0.f;
    if (i1) v = fmaf(c1, i1[idx], v);
    if (i2) v = fmaf(c2, i2[idx], v);
    if (i3) v = fmaf(c3, i3[idx], v);
    if (i4) v = fmaf(c4, i4[idx], v);
    if ((idx >> 11) == (idx & 2047)) v += dval;
    out[idx] = v;
  }
}

// ---------------- M64 = (double)A + 1e-3 I ----------------
__global__ __launch_bounds__(256)
void k_fill64(const float* __restrict__ A, double* __restrict__ M)
{
  const int total = DIMN * DIMN;
  for (int idx = blockIdx.x * 256 + threadIdx.x; idx < total; idx += gridDim.x * 256) {
    double v = (double)A[idx];
    if ((idx >> 11) == (idx & 2047)) v += 1e-3;
    M[idx] = v;
  }
}

// ---------------- split f32 -> bf16 hi/lo (linear only) ----------------
__global__ __launch_bounds__(256)
void k_split(const float* __restrict__ in, unsigned short* __restrict__ hi,
             unsigned short* __restrict__ lo)
{
  const int i4 = blockIdx.x * 256 + threadIdx.x;   // grid 4096
  const float4 v = ((const float4*)in)[i4];
  ushort4 h, l;
  split1(v.x, h.x, l.x); split1(v.y, h.y, l.y);
  split1(v.z, h.z, l.z); split1(v.w, h.w, l.w);
  ((ushort4*)hi)[i4] = h;
  ((ushort4*)lo)[i4] = l;
}

// ---------------- split f32 -> bf16 hi/lo, BOTH linear and transposed ----------------
__global__ __launch_bounds__(256)
void k_splitboth(const float* __restrict__ in,
                 unsigned short* __restrict__ hi, unsigned short* __restrict__ lo,
                 unsigned short* __restrict__ hiT, unsigned short* __restrict__ loT)
{
  __shared__ float t[32][33];
  const int bx = blockIdx.x * 32, by = blockIdx.y * 32;
  const int lx = threadIdx.x, ly = threadIdx.y; // (32,8)
  for (int dy = 0; dy < 32; dy += 8) {
    const size_t o = (size_t)(by + ly + dy) * DIMN + bx + lx;
    const float v = in[o];
    t[ly + dy][lx] = v;
    unsigned short h, l;
    split1(v, h, l);
    hi[o] = h; lo[o] = l;
  }
  __syncthreads();
  for (int dy = 0; dy < 32; dy += 8) {
    const size_t o = (size_t)(bx + ly + dy) * DIMN + by + lx;
    unsigned short h, l;
    split1(t[lx][ly + dy], h, l);
    hiT[o] = h; loT[o] = l;
  }
}

// ---------------- fused: H = c1*i1 + c2*i2, emit TRANSPOSED bf16 splits ----------------
__global__ __launch_bounds__(256)
void k_combsplitT(const float* __restrict__ i1, float c1,
                  const float* __restrict__ i2, float c2,
                  unsigned short* __restrict__ hiT, unsigned short* __restrict__ loT)
{
  __shared__ float t[32][33];
  const int bx = blockIdx.x * 32, by = blockIdx.y * 32;
  const int lx = threadIdx.x, ly = threadIdx.y; // (32,8)
  for (int dy = 0; dy < 32; dy += 8) {
    const size_t o = (size_t)(by + ly + dy) * DIMN + bx + lx;
    t[ly + dy][lx] = fmaf(c1, i1[o], c2 * i2[o]);
  }
  __syncthreads();
  for (int dy = 0; dy < 32; dy += 8) {
    const size_t o = (size_t)(bx + ly + dy) * DIMN + by + lx;
    unsigned short h, l;
    split1(t[lx][ly + dy], h, l);
    hiT[o] = h; loT[o] = l;
  }
}

// ---------------- bf16x3 MFMA GEMM (XCD-swizzled): C = alpha*(A*B) + c1*E1 + c2*E2 ----------------
__global__ __launch_bounds__(256)
void k_gemm3(const unsigned short* __restrict__ Ahg, const unsigned short* __restrict__ Alg,
             const unsigned short* __restrict__ Bhg, const unsigned short* __restrict__ Blg,
             float* __restrict__ C, float alpha,
             const float* E1, float c1, const float* E2, float c2)
{
  __shared__ unsigned short sAh[128 * ALD];
  __shared__ unsigned short sAl[128 * ALD];
  __shared__ unsigned short sBh[128 * ALD];
  __shared__ unsigned short sBl[128 * ALD];
  const int tid = threadIdx.x;
  const int wid = tid >> 6, lane = tid & 63;
  const int lr = lane & 15, lg = lane >> 4;
  const int wm = wid >> 1, wn = wid & 1;
  // XCD swizzle: grid is 16x16 = 256 blocks; 256 % 8 == 0 -> bijective chunked map
  const int bid0 = blockIdx.y * 16 + blockIdx.x;
  const int bids = (bid0 & 7) * 32 + (bid0 >> 3);
  const int brow = (bids >> 4) * 128, bcol = (bids & 15) * 128;
  const int sr = tid >> 1, sh = (tid & 1) * 16;

  const unsigned short* gAh = Ahg + (size_t)(brow + sr) * DIMN + sh;
  const unsigned short* gAl = Alg + (size_t)(brow + sr) * DIMN + sh;
  const unsigned short* gBh = Bhg + (size_t)(bcol + sr) * DIMN + sh;
  const unsigned short* gBl = Blg + (size_t)(bcol + sr) * DIMN + sh;

  f32x4 acc[4][4];
#pragma unroll
  for (int mf = 0; mf < 4; ++mf)
#pragma unroll
    for (int nf = 0; nf < 4; ++nf) acc[mf][nf] = (f32x4){0.f, 0.f, 0.f, 0.f};

  uint4 pa0 = *(const uint4*)gAh;      uint4 pa1 = *(const uint4*)(gAh + 8);
  uint4 pb0 = *(const uint4*)gAl;      uint4 pb1 = *(const uint4*)(gAl + 8);
  uint4 pc0 = *(const uint4*)gBh;      uint4 pc1 = *(const uint4*)(gBh + 8);
  uint4 pd0 = *(const uint4*)gBl;      uint4 pd1 = *(const uint4*)(gBl + 8);

  const int nk = DIMN / 32;
  for (int kt = 0; kt < nk; ++kt) {
    *(uint4*)&sAh[sr * ALD + sh] = pa0;  *(uint4*)&sAh[sr * ALD + sh + 8] = pa1;
    *(uint4*)&sAl[sr * ALD + sh] = pb0;  *(uint4*)&sAl[sr * ALD + sh + 8] = pb1;
    *(uint4*)&sBh[sr * ALD + sh] = pc0;  *(uint4*)&sBh[sr * ALD + sh + 8] = pc1;
    *(uint4*)&sBl[sr * ALD + sh] = pd0;  *(uint4*)&sBl[sr * ALD + sh + 8] = pd1;
    __syncthreads();
    if (kt + 1 < nk) {
      const int o = (kt + 1) * 32;
      pa0 = *(const uint4*)(gAh + o);  pa1 = *(const uint4*)(gAh + o + 8);
      pb0 = *(const uint4*)(gAl + o);  pb1 = *(const uint4*)(gAl + o + 8);
      pc0 = *(const uint4*)(gBh + o);  pc1 = *(const uint4*)(gBh + o + 8);
      pd0 = *(const uint4*)(gBl + o);  pd1 = *(const uint4*)(gBl + o + 8);
    }
    short8 bh[4], bl[4];
#pragma unroll
    for (int nf = 0; nf < 4; ++nf) {
      const int br = 64 * wn + 16 * nf + lr;
      bh[nf] = *(const short8*)&sBh[br * ALD + lg * 8];
      bl[nf] = *(const short8*)&sBl[br * ALD + lg * 8];
    }
#pragma unroll
    for (int mf = 0; mf < 4; ++mf) {
      const int ar = 64 * wm + 16 * mf + lr;
      const short8 ah = *(const short8*)&sAh[ar * ALD + lg * 8];
      const short8 al = *(const short8*)&sAl[ar * ALD + lg * 8];
#pragma unroll
      for (int nf = 0; nf < 4; ++nf) {
        acc[mf][nf] = __builtin_amdgcn_mfma_f32_16x16x32_bf16(ah, bh[nf], acc[mf][nf], 0, 0, 0);
        acc[mf][nf] = __builtin_amdgcn_mfma_f32_16x16x32_bf16(ah, bl[nf], acc[mf][nf], 0, 0, 0);
        acc[mf][nf] = __builtin_amdgcn_mfma_f32_16x16x32_bf16(al, bh[nf], acc[mf][nf], 0, 0, 0);
      }
    }
    __syncthreads();
  }
#pragma unroll
  for (int mf = 0; mf < 4; ++mf) {
#pragma unroll
    for (int nf = 0; nf < 4; ++nf) {
      const int col = bcol + 64 * wn + 16 * nf + lr;
#pragma unroll
      for (int i = 0; i < 4; ++i) {
        const int row = brow + 64 * wm + 16 * mf + 4 * lg + i;
        float v = alpha * acc[mf][nf][i];
        if (E1) v = fmaf(c1, E1[(size_t)row * DIMN + col], v);
        if (E2) v = fmaf(c2, E2[(size_t)row * DIMN + col], v);
        C[(size_t)row * DIMN + col] = v;
      }
    }
  }
}

// ---------------- trailing update (f64, 128x128 tile, XCD-swizzled): M -= Cp*Rp ----------------
__global__ __launch_bounds__(256, 1)
void k_dtrail(const double* __restrict__ Cp, const double* __restrict__ Rp,
              double* __restrict__ M)
{
  __shared__ double As[8][TBM];   // As[kk][row]
  __shared__ double Bs[8][TBM];   // Bs[kk][col]
  const int tid = threadIdx.x;
  const int bid0 = blockIdx.y * 16 + blockIdx.x;
  const int bids = (bid0 & 7) * 32 + (bid0 >> 3);
  const int brow = (bids >> 4) * TBM, bcol = (bids & 15) * TBM;
  const int tx = tid & 15, ty = tid >> 4;

  const int ar = tid >> 1, ac = (tid & 1) * 4;    // A: 128 rows x 8 k
  const int br = tid >> 5, bc = (tid & 31) * 4;   // B: 8 k x 128 cols

  const double* Ap = Cp + (size_t)(brow + ar) * 64 + ac;
  const double* Bp = Rp + (size_t)br * DIMN + (bcol + bc);

  double4 aPre = *(const double4*)Ap;
  double4 bPre = *(const double4*)Bp;

  double acc[8][8];
#pragma unroll
  for (int i = 0; i < 8; ++i)
#pragma unroll
    for (int j = 0; j < 8; ++j) acc[i][j] = 0.0;

  for (int kt = 0; kt < 8; ++kt) {
    As[ac + 0][ar] = aPre.x; As[ac + 1][ar] = aPre.y;
    As[ac + 2][ar] = aPre.z; As[ac + 3][ar] = aPre.w;
    *(double4*)&Bs[br][bc] = bPre;
    __syncthreads();
    if (kt + 1 < 8) {
      aPre = *(const double4*)(Ap + (kt + 1) * 8);
      bPre = *(const double4*)(Bp + (size_t)(kt + 1) * 8 * DIMN);
    }
#pragma unroll
    for (int kk = 0; kk < 8; ++kk) {
      double a[8], b[8];
#pragma unroll
      for (int i = 0; i < 8; ++i) a[i] = As[kk][ty * 8 + i];
#pragma unroll
      for (int j = 0; j < 8; ++j) b[j] = Bs[kk][tx * 8 + j];
#pragma unroll
      for (int i = 0; i < 8; ++i)
#pragma unroll
        for (int j = 0; j < 8; ++j)
          acc[i][j] = fma(a[i], b[j], acc[i][j]);
    }
    __syncthreads();
  }
#pragma unroll
  for (int i = 0; i < 8; ++i) {
    const size_t ro = (size_t)(brow + ty * 8 + i) * DIMN + bcol + tx * 8;
    double4 m0 = *(const double4*)&M[ro];
    double4 m1 = *(const double4*)&M[ro + 4];
    m0.x -= acc[i][0]; m0.y -= acc[i][1]; m0.z -= acc[i][2]; m0.w -= acc[i][3];
    m1.x -= acc[i][4]; m1.y -= acc[i][5]; m1.z -= acc[i][6]; m1.w -= acc[i][7];
    *(double4*)&M[ro] = m0;
    *(double4*)&M[ro + 4] = m1;
  }
}

// ---------------- gj64 v6: UNPIVOTED 64x64 f64 GJ, col-major LDS panel ----------------
__global__ __launch_bounds__(256)
void k_gj64(const double* __restrict__ M, int ldm, double* __restrict__ W, int ldw)
{
  __shared__ double a[128][GJP];   // a[c][r] = P[r][c]; [A | I] col-major
  const int tid = threadIdx.x;
  const int rg = tid & 7;          // rows [8rg, 8rg+8)
  const int cg = tid >> 3;         // 0..31

  for (int idx = tid; idx < 64 * 64; idx += 256) {
    const int r = idx >> 6, c = idx & 63;
    a[c][r] = M[(size_t)r * ldm + c];
    a[64 + c][r] = (r == c) ? 1.0 : 0.0;
  }
  __syncthreads();

  for (int p = 0; p < 64; ++p) {
    const double rpv = 1.0 / a[p][p];
    const int c0 = p + 1 + cg;
    const int c1 = c0 + 32;
    const double prs0 = a[c0][p] * rpv;
    const double prs1 = a[c1][p] * rpv;
    double colp[8];
#pragma unroll
    for (int k = 0; k < 4; ++k) {
      const double2 t2 = *(const double2*)&a[p][rg * 8 + 2 * k];
      colp[2 * k] = t2.x; colp[2 * k + 1] = t2.y;
    }
    __syncthreads();
#pragma unroll
    for (int k = 0; k < 8; ++k) {
      const int r = rg * 8 + k;
      const bool isp = (r == p);
      const double v0 = a[c0][r];
      const double v1 = a[c1][r];
      a[c0][r] = isp ? prs0 : fma(-colp[k], prs0, v0);
      a[c1][r] = isp ? prs1 : fma(-colp[k], prs1, v1);
    }
    __syncthreads();
  }

  for (int idx = tid; idx < 64 * 64; idx += 256) {
    const int r = idx >> 6, c = idx & 63;
    W[(size_t)r * ldw + c] = a[64 + c][r];
  }
}

// ---------------- stagefix: blocks 0-31 rowscale; blocks 32-543 colprep ----------------
#define DBM 64
#define DBK 8
__global__ __launch_bounds__(256)
void k_stagefix(const double* __restrict__ Dinv, double* __restrict__ M,
                double* __restrict__ Rpan, double* __restrict__ Cpan, int p)
{
  const int blk = blockIdx.x;
  const int tid = threadIdx.x;
  if (blk >= 32) {
    const int idx = (blk - 32) * 256 + tid;   // 2048*64 total
    const int i = idx >> 6, k = idx & 63;
    const bool inP = (i >> 6) == p;
    const size_t mo = (size_t)i * DIMN + p * 64 + k;
    double v = 0.0;
    if (!inP) { v = M[mo]; M[mo] = 0.0; }
    Cpan[idx] = v;
    return;
  }
  __shared__ double As[DBK][DBM];
  __shared__ double Bs[DBK][DBM];
  const double* Mrow = M + (size_t)p * 64 * DIMN;
  const int tx = tid & 15, ty = tid >> 4;
  const int bcol = blk * DBM;

  const int arow = tid >> 2, ac0 = (tid & 3) * 2;
  const int brw  = tid >> 5, bc0 = (tid & 31) * 2;

  const double* Aptr = Dinv + (size_t)arow * 64 + ac0;
  const double* Bptr = Mrow + (size_t)brw * DIMN + (bcol + bc0);

  double2 aPre = *(const double2*)Aptr;
  double2 bPre = *(const double2*)Bptr;

  double acc[4][4];
#pragma unroll
  for (int i = 0; i < 4; ++i)
#pragma unroll
    for (int j = 0; j < 4; ++j) acc[i][j] = 0.0;

  for (int kt = 0; kt < 8; ++kt) {
    As[ac0 + 0][arow] = aPre.x;
    As[ac0 + 1][arow] = aPre.y;
    Bs[brw][bc0 + 0] = bPre.x;
    Bs[brw][bc0 + 1] = bPre.y;
    __syncthreads();
    if (kt + 1 < 8) {
      aPre = *(const double2*)(Aptr + (size_t)(kt + 1) * DBK);
      bPre = *(const double2*)(Bptr + (size_t)(kt + 1) * DBK * DIMN);
    }
#pragma unroll
    for (int kk = 0; kk < DBK; ++kk) {
      double a[4], b[4];
#pragma unroll
      for (int i = 0; i < 4; ++i) a[i] = As[kk][ty * 4 + i];
#pragma unroll
      for (int j = 0; j < 4; ++j) b[j] = Bs[kk][tx * 4 + j];
#pragma unroll
      for (int i = 0; i < 4; ++i)
#pragma unroll
        for (int j = 0; j < 4; ++j)
          acc[i][j] = fma(a[i], b[j], acc[i][j]);
    }
    __syncthreads();
  }
  const bool pivcol = (bcol >> 6) == p;
#pragma unroll
  for (int i = 0; i < 4; ++i) {
    const int gi = ty * 4 + i;
#pragma unroll
    for (int j = 0; j < 4; ++j) {
      const int gj = bcol + tx * 4 + j;
      double v = pivcol ? Dinv[(size_t)gi * 64 + (gj & 63)] : acc[i][j];
      Rpan[(size_t)gi * DIMN + gj] = v;
      M[(size_t)(p * 64 + gi) * DIMN + gj] = v;
    }
  }
}

// ---------------- matvec f32 matrix, f64 vectors ----------------
__global__ __launch_bounds__(256)
void k_mv(const float* __restrict__ Mat, const double* __restrict__ vin,
          double* vout, const double* vadd, double alpha)
{
  const int lane = threadIdx.x & 63;
  const int row = blockIdx.x * 4 + (threadIdx.x >> 6);
  const float* mrow = Mat + (size_t)row * DIMN;
  double acc = 0.0;
  for (int p = 0; p < DIMN; p += 256) {
    const float4 m = *(const float4*)&mrow[p + lane * 4];
    const double* vp = &vin[p + lane * 4];
    acc += (double)m.x * vp[0] + (double)m.y * vp[1] + (double)m.z * vp[2] + (double)m.w * vp[3];
  }
  for (int off = 32; off; off >>= 1) acc += __shfl_down(acc, off);
  if (lane == 0) vout[row] = alpha * acc + (vadd ? vadd[row] : 0.0);
}

// ---------------- matvec f64 matrix ----------------
__global__ __launch_bounds__(256)
void k_mv64(const double* __restrict__ W, const double* __restrict__ vin,
            double* vout, const double* vadd, double alpha)
{
  const int lane = threadIdx.x & 63;
  const int row = blockIdx.x * 4 + (threadIdx.x >> 6);
  const double* mrow = W + (size_t)row * DIMN;
  double acc = 0.0;
  for (int p = 0; p < DIMN; p += 256) {
    const int idx = p + lane * 4;
    const double2 m0 = *(const double2*)&mrow[idx];
    const double2 m1 = *(const double2*)&mrow[idx + 2];
    acc += m0.x * vin[idx] + m0.y * vin[idx + 1] + m1.x * vin[idx + 2] + m1.y * vin[idx + 3];
  }
  for (int off = 32; off; off >>= 1) acc += __shfl_down(acc, off);
  if (lane == 0) vout[row] = alpha * acc + (vadd ? vadd[row] : 0.0);
}

// ---------------- residual: r = y - (A*x + 1e-3*x) ----------------
__global__ __launch_bounds__(256)
void k_mvres(const float* __restrict__ A, const double* __restrict__ x,
             const double* __restrict__ y, double* r)
{
  const int lane = threadIdx.x & 63;
  const int row = blockIdx.x * 4 + (threadIdx.x >> 6);
  const float* mrow = A + (size_t)row * DIMN;
  double acc = 0.0;
  for (int p = 0; p < DIMN; p += 256) {
    const float4 m = *(const float4*)&mrow[p + lane * 4];
    const double* vp = &x[p + lane * 4];
    acc += (double)m.x * vp[0] + (double)m.y * vp[1] + (double)m.z * vp[2] + (double)m.w * vp[3];
  }
  for (int off = 32; off; off >>= 1) acc += __shfl_down(acc, off);
  if (lane == 0) r[row] = y[row] - acc - 1e-3 * x[row];
}

// ---------------- transpose 2048x2048 f32 ----------------
__global__ __launch_bounds__(256)
void k_transpose(const float* __restrict__ in, float* __restrict__ out)
{
  __shared__ float t[32][33];
  const int bx = blockIdx.x * 32, by = blockIdx.y * 32;
  const int lx = threadIdx.x, ly = threadIdx.y;
  for (int dy = 0; dy < 32; dy += 8)
    t[ly + dy][lx] = in[(size_t)(by + ly + dy) * DIMN + bx + lx];
  __syncthreads();
  for (int dy = 0; dy < 32; dy += 8)
    out[(size_t)(bx + ly + dy) * DIMN + by + lx] = t[lx][ly + dy];
}

// ---------------- chain step (bootstrap): vout=(I+E)vin; uout=(I+ERT)uin ----------------
__global__ __launch_bounds__(256)
void k_chain(const float* __restrict__ E, const float* __restrict__ vin, float* __restrict__ vout,
             const float* __restrict__ ERT, const float* __restrict__ uin, float* __restrict__ uout)
{
  const int lane = threadIdx.x & 63;
  const int w = threadIdx.x >> 6;
  const int b = blockIdx.x;
  const float* mrow; const float* xin; float* xout; int row;
  if (b < 512) { row = b * 4 + w; mrow = E + (size_t)row * DIMN; xin = vin; xout = vout; }
  else { row = (b - 512) * 4 + w; mrow = ERT + (size_t)row * DIMN; xin = uin; xout = uout; }
  float acc = 0.f;
  for (int p = 0; p < DIMN; p += 256) {
    const float4 m = *(const float4*)&mrow[p + lane * 4];
    const float* vp = &xin[p + lane * 4];
    acc = fmaf(m.x, vp[0], acc);
    acc = fmaf(m.y, vp[1], acc);
    acc = fmaf(m.z, vp[2], acc);
    acc = fmaf(m.w, vp[3], acc);
  }
  for (int off = 32; off; off >>= 1) acc += __shfl_down(acc, off);
  if (lane == 0) xout[row] = xin[row] + acc;
}

// ---------------- batched chain: 8 V-steps (E8) + 4 U-steps (ER4T) per launch ----------------
__global__ __launch_bounds__(256)
void k_chainb(const float* __restrict__ E8, const float* __restrict__ Vin,
              float* __restrict__ Vout, int do_v,
              const float* __restrict__ A4T, const float* __restrict__ Uin,
              float* __restrict__ Uout)
{
  const int lane = threadIdx.x & 63;
  const int w = threadIdx.x >> 6;
  const int b = blockIdx.x;
  if (b < 512) {
    if (!do_v) return;
    const int row = b * 4 + w;
    const float* mrow = E8 + (size_t)row * DIMN;
    float acc[8];
#pragma unroll
    for (int r = 0; r < 8; ++r) acc[r] = 0.f;
    for (int p = 0; p < DIMN; p += 256) {
      const float4 m = *(const float4*)&mrow[p + lane * 4];
#pragma unroll
      for (int r = 0; r < 8; ++r) {
        const float4 v = *(const float4*)&Vin[(size_t)r * DIMN + p + lane * 4];
        acc[r] = fmaf(m.x, v.x, acc[r]);
        acc[r] = fmaf(m.y, v.y, acc[r]);
        acc[r] = fmaf(m.z, v.z, acc[r]);
        acc[r] = fmaf(m.w, v.w, acc[r]);
      }
    }
#pragma unroll
    for (int r = 0; r < 8; ++r) {
      float a = acc[r];
      for (int off = 32; off; off >>= 1) a += __shfl_down(a, off);
      if (lane == 0) Vout[(size_t)r * DIMN + row] = Vin[(size_t)r * DIMN + row] + a;
    }
  } else {
    const int row = (b - 512) * 4 + w;
    const float* mrow = A4T + (size_t)row * DIMN;
    float acc[4];
#pragma unroll
    for (int r = 0; r < 4; ++r) acc[r] = 0.f;
    for (int p = 0; p < DIMN; p += 256) {
      const float4 m = *(const float4*)&mrow[p + lane * 4];
#pragma unroll
      for (int r = 0; r < 4; ++r) {
        const float4 v = *(const float4*)&Uin[(size_t)r * DIMN + p + lane * 4];
        acc[r] = fmaf(m.x, v.x, acc[r]);
        acc[r] = fmaf(m.y, v.y, acc[r]);
        acc[r] = fmaf(m.z, v.z, acc[r]);
        acc[r] = fmaf(m.w, v.w, acc[r]);
      }
    }
#pragma unroll
    for (int r = 0; r < 4; ++r) {
      float a = acc[r];
      for (int off = 32; off; off >>= 1) a += __shfl_down(a, off);
      if (lane == 0) Uout[(size_t)r * DIMN + row] = Uin[(size_t)r * DIMN + row] + a;
    }
  }
}

// ---------------- terms: out[8191-t] = dot(U[t/91], V[t%91]) ----------------
__global__ __launch_bounds__(256)
void k_terms(const float* __restrict__ U, const float* __restrict__ V, float* __restrict__ out)
{
  const int lane = threadIdx.x & 63;
  const int t = blockIdx.x * 4 + (threadIdx.x >> 6);
  const int j = t / RSPLIT, i = t - j * RSPLIT;
  const float* u = U + (size_t)j * DIMN;
  const float* v = V + (size_t)i * DIMN;
  float acc = 0.f;
  for (int p = 0; p < DIMN; p += 256) {
    const float4 a4 = *(const float4*)&u[p + lane * 4];
    const float4 b4 = *(const float4*)&v[p + lane * 4];
    acc = fmaf(a4.x, b4.x, acc); acc = fmaf(a4.y, b4.y, acc);
    acc = fmaf(a4.z, b4.z, acc); acc = fmaf(a4.w, b4.w, acc);
  }
  for (int off = 32; off; off >>= 1) acc += __shfl_down(acc, off);
  if (lane == 0) out[MSTEPS - 1 - t] = acc;
}

// ---------------- small vector inits ----------------
__global__ void k_vecinit(const float* __restrict__ B, double* __restrict__ b64,
                          const float* __restrict__ Cv, float* __restrict__ U0)
{
  const int i = blockIdx.x * 256 + threadIdx.x;
  if (i < DIMN) { b64[i] = 0.01 * (double)B[i]; U0[i] = Cv[i]; }
}
__global__ void k_v0(const double* __restrict__ x64, float* __restrict__ V0)
{
  const int i = blockIdx.x * 256 + threadIdx.x;
  if (i < DIMN) V0[i] = (float)x64[i];
}

extern "C" void kernel_launch(void* const* d_in, const int* in_sizes, int n_in,
                              void* d_out, int out_size, void* d_ws, size_t ws_size,
                              hipStream_t stream)
{
  const float* dA = (const float*)d_in[0];
  const float* dB = (const float*)d_in[1];
  const float* dC = (const float*)d_in[2];
  float* out = (float*)d_out;

  float* fb = (float*)d_ws;
  float* Ebuf = fb;                 // Ath/Atl (bf16) -> E (f32, bootstrap V)
  float* t1 = fb + NN;              // M64 lo/W lo -> Y2 splits -> E8 (f32, batch V)
  float* t2 = t1 + NN;              // M64 hi/W hi -> Hth/Htl splits
  float* t3 = t2 + NN;              // Y2 (f32) -> ER4T (f32, batch U)
  float* t4 = t3 + NN;              // Ah/Al -> ER -> ER4
  float* t5 = t4 + NN;              // ERT (f32, bootstrap U)
  double* M64 = (double*)t1;        // spans t1,t2
  double* scr64 = (double*)(fb + 6 * NN);
  double* Dinv = scr64;                        // 64x64
  double* Cpan = Dinv + 64 * 64;               // 2048x64
  double* Rpan = Cpan + (size_t)DIMN * 64;     // 64x2048
  double* y64 = Rpan + (size_t)DIMN * 64;
  double* x64 = y64 + DIMN;
  double* r64 = x64 + DIMN;
  double* b64 = r64 + DIMN;
  float* V  = (float*)(b64 + DIMN);            // 96 x 2048
  float* Uc = V + (size_t)96 * DIMN;           // 92 x 2048

  const size_t needed = 6 * NN * 4
                        + (64 * 64 + 2 * (size_t)DIMN * 64 + 4 * (size_t)DIMN) * 8
                        + (size_t)(96 + 92) * DIMN * 4;
  if (ws_size < needed) return;

  const float* NUL = nullptr;
  dim3 cb(256), cg(2048);

  unsigned short* Ah  = (unsigned short*)t4;   unsigned short* Al  = Ah + NN;
  unsigned short* Ath = (unsigned short*)Ebuf; unsigned short* Atl = Ath + NN;
  unsigned short* Y2h = (unsigned short*)t1;   unsigned short* Y2l = Y2h + NN;
  unsigned short* Hth = (unsigned short*)t2;   unsigned short* Htl = Hth + NN;

  // ---- Phase 0: bf16 splits of A (both layouts, one pass); Y2; E ----
  k_splitboth<<<dim3(64, 64), dim3(32, 8), 0, stream>>>(dA, Ah, Al, Ath, Atl);
  k_gemm3<<<dim3(16, 16), cb, 0, stream>>>(Ah, Al, Ath, Atl, t3, 0.8281f,
                                           NUL, 0.f, NUL, 0.f);                 // Y2
  k_combine4<<<cg, cb, 0, stream>>>(Ebuf, t3, (float)(5e-5 / 0.8281), dA, 0.01f,
                                    NUL, 0, NUL, 0, 0.f);                       // E

  // ---- Phase 1: M64 = A + 1e-3 I; flat blocked GJ inversion in place (f64) ----
  k_fill64<<<cg, cb, 0, stream>>>(dA, M64);
  for (int p = 0; p < NBLK; ++p) {
    double* Mrow = M64 + (size_t)p * 64 * DIMN;
    k_gj64<<<dim3(1), cb, 0, stream>>>(Mrow + p * 64, DIMN, Dinv, 64);
    k_stagefix<<<dim3(544), cb, 0, stream>>>(Dinv, M64, Rpan, Cpan, p);
    k_dtrail<<<dim3(16, 16), cb, 0, stream>>>(Cpan, Rpan, M64);
  }

  // ---- Phase 3: Bbar: y = E*(0.01B); x = W*y; 1x f64 IR ----
  k_vecinit<<<dim3(8), cb, 0, stream>>>(dB, b64, dC, Uc);
  k_mv<<<dim3(512), cb, 0, stream>>>(Ebuf, b64, y64, (const double*)nullptr, 1.0);
  k_mv64<<<dim3(512), cb, 0, stream>>>(M64, y64, x64, (const double*)nullptr, 1.0);
  k_mvres<<<dim3(512), cb, 0, stream>>>(dA, x64, y64, r64);
  k_mv64<<<dim3(512), cb, 0, stream>>>(M64, r64, x64, x64, 1.0);
  k_v0<<<dim3(8), cb, 0, stream>>>(x64, V);                                     // V[0] = Bbar

  // ---- Phase 4: ER, ER4 (bf16x3 GEMMs), E8 (elementwise), transposes ----
  k_split<<<dim3(4096), cb, 0, stream>>>(t3, Y2h, Y2l);                         // W dead
  k_combsplitT<<<dim3(64, 64), dim3(32, 8), 0, stream>>>(dA, 0.91f / 6.f,
                                                         t3, 1.f / 24.f, Hth, Htl); // H^T splits
  k_gemm3<<<dim3(16, 16), cb, 0, stream>>>(Y2h, Y2l, Hth, Htl, t4, 1.f,
                                           t3, 0.5f, dA, 0.91f);                // ER -> t4
  k_transpose<<<dim3(64, 64), dim3(32, 8), 0, stream>>>(t4, t5);                // ERT -> t5
  k_combsplitT<<<dim3(64, 64), dim3(32, 8), 0, stream>>>(dA, 3.64f / 6.f,
                                                         t3, 16.f / 24.f, Hth, Htl); // H4^T splits
  k_gemm3<<<dim3(16, 16), cb, 0, stream>>>(Y2h, Y2l, Hth, Htl, t4, 16.f,
                                           t3, 8.f, dA, 3.64f);                 // ER4 -> t4
  k_combine4<<<cg, cb, 0, stream>>>(t1, dA, 0.08f, t3, (float)(0.0032 / 0.8281),
                                    NUL, 0, NUL, 0, 0.f);                       // E8 -> t1
  k_transpose<<<dim3(64, 64), dim3(32, 8), 0, stream>>>(t4, t3);                // ER4T -> t3

  // ---- Phase 5: bootstrap (7 serial) + 22 batched launches + terms ----
  for (int s = 0; s < 7; ++s) {
    k_chain<<<dim3(1024), cb, 0, stream>>>(Ebuf, V + (size_t)s * DIMN, V + (size_t)(s + 1) * DIMN,
                                           t5, Uc + (size_t)s * DIMN, Uc + (size_t)(s + 1) * DIMN);
  }
  for (int i = 0; i < 22; ++i) {
    k_chainb<<<dim3(1024), cb, 0, stream>>>(
        t1, V + (size_t)(8 * i) * DIMN, V + (size_t)(8 * i + 8) * DIMN, (i < 11) ? 1 : 0,
        t3, Uc + (size_t)(4 * i) * DIMN, Uc + (size_t)(4 * i + 4) * DIMN);
  }
  k_terms<<<dim3(2048), cb, 0, stream>>>(Uc, V, out);
}

// Round 13
// 4268.923 us; speedup vs baseline: 1.0366x; 1.0366x over previous
//
#include <hip/hip_runtime.h>
#include <hip/hip_bf16.h>

// ZOH linear layer: K[1,8192], dim 2048.
// Y2=(0.91A)^2 (bf16x3 MFMA gemm, fused E epilogue); ER, ER4 via bf16x3 gemms.
// W=inv(A+1e-3 I) f64 in-place flat blocked GJ; per stage: stagefix (rowscale+colprep)
// then k_ftrail = trailing update (1024x 64x64 tiles) FUSED with next stage's 64x64
// in-place Jordan inversion (block 0 = diag tile, overlaps the trailing). + 1 f64 IR.
// K[91j+i] = (C*AR^j)·(A^i*Bbar): bootstrap 7 serial + 22 batched chain launches + dots.

#define DIMN 2048
#define MSTEPS 8192
#define RSPLIT 91
#define NN ((size_t)DIMN * DIMN)
#define NBLK 32
#define ALD 36   // LDS pitch (bf16) for gemm3
#define GJP 65   // gj64 panel pitch (f64)

typedef short short8 __attribute__((ext_vector_type(8)));
typedef float f32x4 __attribute__((ext_vector_type(4)));

__device__ inline void split1(float x, unsigned short& h, unsigned short& l)
{
  __hip_bfloat16 b = __float2bfloat16(x);
  h = *reinterpret_cast<unsigned short*>(&b);
  float r = x - __bfloat162float(b);
  __hip_bfloat16 b2 = __float2bfloat16(r);
  l = *reinterpret_cast<unsigned short*>(&b2);
}

// ---------------- elementwise f32: out = c1*i1+c2*i2 + dval*I ----------------
__global__ __launch_bounds__(256)
void k_combine4(float* out,
                const float* i1, float c1, const float* i2, float c2,
                const float* i3, float c3, const float* i4, float c4,
                float dval)
{
  const int total = DIMN * DIMN;
  for (int idx = blockIdx.x * 256 + threadIdx.x; idx < total; idx += gridDim.x * 256) {
    float v = 0.f;
    if (i1) v = fmaf(c1, i1[idx], v);
    if (i2) v = fmaf(c2, i2[idx], v);
    if (i3) v = fmaf(c3, i3[idx], v);
    if (i4) v = fmaf(c4, i4[idx], v);
    if ((idx >> 11) == (idx & 2047)) v += dval;
    out[idx] = v;
  }
}

// ---------------- M64 = (double)A + 1e-3 I ----------------
__global__ __launch_bounds__(256)
void k_fill64(const float* __restrict__ A, double* __restrict__ M)
{
  const int total = DIMN * DIMN;
  for (int idx = blockIdx.x * 256 + threadIdx.x; idx < total; idx += gridDim.x * 256) {
    double v = (double)A[idx];
    if ((idx >> 11) == (idx & 2047)) v += 1e-3;
    M[idx] = v;
  }
}

// ---------------- split f32 -> bf16 hi/lo (linear only) ----------------
__global__ __launch_bounds__(256)
void k_split(const float* __restrict__ in, unsigned short* __restrict__ hi,
             unsigned short* __restrict__ lo)
{
  const int i4 = blockIdx.x * 256 + threadIdx.x;   // grid 4096
  const float4 v = ((const float4*)in)[i4];
  ushort4 h, l;
  split1(v.x, h.x, l.x); split1(v.y, h.y, l.y);
  split1(v.z, h.z, l.z); split1(v.w, h.w, l.w);
  ((ushort4*)hi)[i4] = h;
  ((ushort4*)lo)[i4] = l;
}

// ---------------- split f32 -> bf16 hi/lo, BOTH linear and transposed ----------------
__global__ __launch_bounds__(256)
void k_splitboth(const float* __restrict__ in,
                 unsigned short* __restrict__ hi, unsigned short* __restrict__ lo,
                 unsigned short* __restrict__ hiT, unsigned short* __restrict__ loT)
{
  __shared__ float t[32][33];
  const int bx = blockIdx.x * 32, by = blockIdx.y * 32;
  const int lx = threadIdx.x, ly = threadIdx.y; // (32,8)
  for (int dy = 0; dy < 32; dy += 8) {
    const size_t o = (size_t)(by + ly + dy) * DIMN + bx + lx;
    const float v = in[o];
    t[ly + dy][lx] = v;
    unsigned short h, l;
    split1(v, h, l);
    hi[o] = h; lo[o] = l;
  }
  __syncthreads();
  for (int dy = 0; dy < 32; dy += 8) {
    const size_t o = (size_t)(bx + ly + dy) * DIMN + by + lx;
    unsigned short h, l;
    split1(t[lx][ly + dy], h, l);
    hiT[o] = h; loT[o] = l;
  }
}

// ---------------- fused: H = c1*i1 + c2*i2, emit TRANSPOSED bf16 splits ----------------
__global__ __launch_bounds__(256)
void k_combsplitT(const float* __restrict__ i1, float c1,
                  const float* __restrict__ i2, float c2,
                  unsigned short* __restrict__ hiT, unsigned short* __restrict__ loT)
{
  __shared__ float t[32][33];
  const int bx = blockIdx.x * 32, by = blockIdx.y * 32;
  const int lx = threadIdx.x, ly = threadIdx.y; // (32,8)
  for (int dy = 0; dy < 32; dy += 8) {
    const size_t o = (size_t)(by + ly + dy) * DIMN + bx + lx;
    t[ly + dy][lx] = fmaf(c1, i1[o], c2 * i2[o]);
  }
  __syncthreads();
  for (int dy = 0; dy < 32; dy += 8) {
    const size_t o = (size_t)(bx + ly + dy) * DIMN + by + lx;
    unsigned short h, l;
    split1(t[lx][ly + dy], h, l);
    hiT[o] = h; loT[o] = l;
  }
}

// ---------------- bf16x3 MFMA GEMM: C = alpha*(A*B) + c1*E1 + c2*E2 ----------------
// Optional 2nd output: O2 = o2ab*(alpha*AB) + o2a*Ab (element-wise, same index).
__global__ __launch_bounds__(256)
void k_gemm3(const unsigned short* __restrict__ Ahg, const unsigned short* __restrict__ Alg,
             const unsigned short* __restrict__ Bhg, const unsigned short* __restrict__ Blg,
             float* __restrict__ C, float alpha,
             const float* E1, float c1, const float* E2, float c2,
             const float* Ab, float* O2, float o2ab, float o2a)
{
  __shared__ unsigned short sAh[128 * ALD];
  __shared__ unsigned short sAl[128 * ALD];
  __shared__ unsigned short sBh[128 * ALD];
  __shared__ unsigned short sBl[128 * ALD];
  const int tid = threadIdx.x;
  const int wid = tid >> 6, lane = tid & 63;
  const int lr = lane & 15, lg = lane >> 4;
  const int wm = wid >> 1, wn = wid & 1;
  const int bid0 = blockIdx.y * 16 + blockIdx.x;
  const int bids = (bid0 & 7) * 32 + (bid0 >> 3);
  const int brow = (bids >> 4) * 128, bcol = (bids & 15) * 128;
  const int sr = tid >> 1, sh = (tid & 1) * 16;

  const unsigned short* gAh = Ahg + (size_t)(brow + sr) * DIMN + sh;
  const unsigned short* gAl = Alg + (size_t)(brow + sr) * DIMN + sh;
  const unsigned short* gBh = Bhg + (size_t)(bcol + sr) * DIMN + sh;
  const unsigned short* gBl = Blg + (size_t)(bcol + sr) * DIMN + sh;

  f32x4 acc[4][4];
#pragma unroll
  for (int mf = 0; mf < 4; ++mf)
#pragma unroll
    for (int nf = 0; nf < 4; ++nf) acc[mf][nf] = (f32x4){0.f, 0.f, 0.f, 0.f};

  uint4 pa0 = *(const uint4*)gAh;      uint4 pa1 = *(const uint4*)(gAh + 8);
  uint4 pb0 = *(const uint4*)gAl;      uint4 pb1 = *(const uint4*)(gAl + 8);
  uint4 pc0 = *(const uint4*)gBh;      uint4 pc1 = *(const uint4*)(gBh + 8);
  uint4 pd0 = *(const uint4*)gBl;      uint4 pd1 = *(const uint4*)(gBl + 8);

  const int nk = DIMN / 32;
  for (int kt = 0; kt < nk; ++kt) {
    *(uint4*)&sAh[sr * ALD + sh] = pa0;  *(uint4*)&sAh[sr * ALD + sh + 8] = pa1;
    *(uint4*)&sAl[sr * ALD + sh] = pb0;  *(uint4*)&sAl[sr * ALD + sh + 8] = pb1;
    *(uint4*)&sBh[sr * ALD + sh] = pc0;  *(uint4*)&sBh[sr * ALD + sh + 8] = pc1;
    *(uint4*)&sBl[sr * ALD + sh] = pd0;  *(uint4*)&sBl[sr * ALD + sh + 8] = pd1;
    __syncthreads();
    if (kt + 1 < nk) {
      const int o = (kt + 1) * 32;
      pa0 = *(const uint4*)(gAh + o);  pa1 = *(const uint4*)(gAh + o + 8);
      pb0 = *(const uint4*)(gAl + o);  pb1 = *(const uint4*)(gAl + o + 8);
      pc0 = *(const uint4*)(gBh + o);  pc1 = *(const uint4*)(gBh + o + 8);
      pd0 = *(const uint4*)(gBl + o);  pd1 = *(const uint4*)(gBl + o + 8);
    }
    short8 bh[4], bl[4];
#pragma unroll
    for (int nf = 0; nf < 4; ++nf) {
      const int br = 64 * wn + 16 * nf + lr;
      bh[nf] = *(const short8*)&sBh[br * ALD + lg * 8];
      bl[nf] = *(const short8*)&sBl[br * ALD + lg * 8];
    }
#pragma unroll
    for (int mf = 0; mf < 4; ++mf) {
      const int ar = 64 * wm + 16 * mf + lr;
      const short8 ah = *(const short8*)&sAh[ar * ALD + lg * 8];
      const short8 al = *(const short8*)&sAl[ar * ALD + lg * 8];
#pragma unroll
      for (int nf = 0; nf < 4; ++nf) {
        acc[mf][nf] = __builtin_amdgcn_mfma_f32_16x16x32_bf16(ah, bh[nf], acc[mf][nf], 0, 0, 0);
        acc[mf][nf] = __builtin_amdgcn_mfma_f32_16x16x32_bf16(ah, bl[nf], acc[mf][nf], 0, 0, 0);
        acc[mf][nf] = __builtin_amdgcn_mfma_f32_16x16x32_bf16(al, bh[nf], acc[mf][nf], 0, 0, 0);
      }
    }
    __syncthreads();
  }
#pragma unroll
  for (int mf = 0; mf < 4; ++mf) {
#pragma unroll
    for (int nf = 0; nf < 4; ++nf) {
      const int col = bcol + 64 * wn + 16 * nf + lr;
#pragma unroll
      for (int i = 0; i < 4; ++i) {
        const int row = brow + 64 * wm + 16 * mf + 4 * lg + i;
        const size_t off = (size_t)row * DIMN + col;
        const float va = alpha * acc[mf][nf][i];
        float v = va;
        if (E1) v = fmaf(c1, E1[off], v);
        if (E2) v = fmaf(c2, E2[off], v);
        C[off] = v;
        if (O2) O2[off] = fmaf(o2ab, va, o2a * Ab[off]);
      }
    }
  }
}

// ---------------- gj64 v6 (stage 0 only): UNPIVOTED 64x64 f64 GJ, col-major LDS ----------------
__global__ __launch_bounds__(256)
void k_gj64(const double* __restrict__ M, int ldm, double* __restrict__ W, int ldw)
{
  __shared__ double a[128][GJP];   // a[c][r] = P[r][c]; [A | I] col-major
  const int tid = threadIdx.x;
  const int rg = tid & 7;
  const int cg = tid >> 3;

  for (int idx = tid; idx < 64 * 64; idx += 256) {
    const int r = idx >> 6, c = idx & 63;
    a[c][r] = M[(size_t)r * ldm + c];
    a[64 + c][r] = (r == c) ? 1.0 : 0.0;
  }
  __syncthreads();

  for (int p = 0; p < 64; ++p) {
    const double rpv = 1.0 / a[p][p];
    const int c0 = p + 1 + cg;
    const int c1 = c0 + 32;
    const double prs0 = a[c0][p] * rpv;
    const double prs1 = a[c1][p] * rpv;
    double colp[8];
#pragma unroll
    for (int k = 0; k < 4; ++k) {
      const double2 t2 = *(const double2*)&a[p][rg * 8 + 2 * k];
      colp[2 * k] = t2.x; colp[2 * k + 1] = t2.y;
    }
    __syncthreads();
#pragma unroll
    for (int k = 0; k < 8; ++k) {
      const int r = rg * 8 + k;
      const bool isp = (r == p);
      const double v0 = a[c0][r];
      const double v1 = a[c1][r];
      a[c0][r] = isp ? prs0 : fma(-colp[k], prs0, v0);
      a[c1][r] = isp ? prs1 : fma(-colp[k], prs1, v1);
    }
    __syncthreads();
  }

  for (int idx = tid; idx < 64 * 64; idx += 256) {
    const int r = idx >> 6, c = idx & 63;
    W[(size_t)r * ldw + c] = a[64 + c][r];
  }
}

// ---------------- ftrail: trailing update (64x64 tiles) fused w/ next-stage Jordan ----------------
// Grid 32x32. Block 0 takes the diagonal tile (sgj,sgj) (swapped so it dispatches first);
// after updating it, runs in-place unpivoted Gauss-Jordan inversion in LDS -> Dinv.
__global__ __launch_bounds__(256)
void k_ftrail(const double* __restrict__ Cp, const double* __restrict__ Rp,
              double* __restrict__ M, double* __restrict__ Dinv, int sgj, int do_gj)
{
  __shared__ double As[8][66];   // Cp chunk [kk][row]
  __shared__ double Bs[8][66];   // Rp chunk [kk][col]
  __shared__ double aj[64][65];  // Jordan panel, col-major aj[c][r]
  const int tid = threadIdx.x;
  const int bid0 = blockIdx.y * 32 + blockIdx.x;
  const int dd = sgj * 32 + sgj;  // diag tile linear id (sgj<32 when do_gj)
  int t = bid0;
  if (do_gj) { if (bid0 == 0) t = dd; else if (bid0 == dd) t = 0; }
  const int tr = t >> 5, tc = t & 31;
  const int brow = tr * 64, bcol = tc * 64;
  const int tx = tid & 15, ty = tid >> 4;

  const int arow = tid >> 2, ac0 = (tid & 3) * 2;   // Cp: 64 rows x 8 k
  const int brw  = tid >> 5, bc0 = (tid & 31) * 2;  // Rp: 8 k x 64 cols

  const double* Ap = Cp + (size_t)(brow + arow) * 64 + ac0;
  const double* Bp = Rp + (size_t)brw * DIMN + (bcol + bc0);
  double2 aPre = *(const double2*)Ap;
  double2 bPre = *(const double2*)Bp;

  double acc[4][4];
#pragma unroll
  for (int i = 0; i < 4; ++i)
#pragma unroll
    for (int j = 0; j < 4; ++j) acc[i][j] = 0.0;

  for (int kt = 0; kt < 8; ++kt) {
    As[ac0 + 0][arow] = aPre.x;
    As[ac0 + 1][arow] = aPre.y;
    Bs[brw][bc0 + 0] = bPre.x;
    Bs[brw][bc0 + 1] = bPre.y;
    __syncthreads();
    if (kt + 1 < 8) {
      aPre = *(const double2*)(Ap + (kt + 1) * 8);
      bPre = *(const double2*)(Bp + (size_t)(kt + 1) * 8 * DIMN);
    }
#pragma unroll
    for (int kk = 0; kk < 8; ++kk) {
      double a[4], b[4];
#pragma unroll
      for (int i = 0; i < 4; ++i) a[i] = As[kk][ty * 4 + i];
#pragma unroll
      for (int j = 0; j < 4; ++j) b[j] = Bs[kk][tx * 4 + j];
#pragma unroll
      for (int i = 0; i < 4; ++i)
#pragma unroll
        for (int j = 0; j < 4; ++j)
          acc[i][j] = fma(a[i], b[j], acc[i][j]);
    }
    __syncthreads();
  }

  // write M_tile -= Cp*Rp, keep values
  double vout[4][4];
#pragma unroll
  for (int i = 0; i < 4; ++i) {
#pragma unroll
    for (int j = 0; j < 4; ++j) {
      const size_t mo = (size_t)(brow + ty * 4 + i) * DIMN + bcol + tx * 4 + j;
      const double v = M[mo] - acc[i][j];
      vout[i][j] = v;
      M[mo] = v;
    }
  }

  if (!(do_gj && tr == sgj && tc == sgj)) return;

  // ---- in-place Jordan inversion of the updated diag tile ----
#pragma unroll
  for (int i = 0; i < 4; ++i)
#pragma unroll
    for (int j = 0; j < 4; ++j)
      aj[tx * 4 + j][ty * 4 + i] = vout[i][j];   // aj[c][r]
  __syncthreads();

  const int rg = tid & 7;       // rows [8rg,8rg+8)
  const int cg = tid >> 3;      // cols {cg, cg+32}
  const int c0 = cg, c1 = cg + 32;
  for (int p = 0; p < 64; ++p) {
    const double d = 1.0 / aj[p][p];
    const double r0d = aj[c0][p] * d;   // new row-p value for col c0
    const double r1d = aj[c1][p] * d;
    double colp[8];
#pragma unroll
    for (int k = 0; k < 4; ++k) {
      const double2 t2 = *(const double2*)&aj[p][rg * 8 + 2 * k];
      colp[2 * k] = t2.x; colp[2 * k + 1] = t2.y;
    }
    __syncthreads();
#pragma unroll
    for (int k = 0; k < 8; ++k) {
      const int r = rg * 8 + k;
      // col c0
      double nv0;
      if (r == p) nv0 = (c0 == p) ? d : r0d;
      else nv0 = (c0 == p) ? (-colp[k] * d) : fma(-colp[k], r0d, aj[c0][r]);
      aj[c0][r] = nv0;
      // col c1 (c1 >= 32 > p possible; c1 == p never since c1 >= 32 and p<64... c1 in [32,63])
      double nv1;
      if (r == p) nv1 = (c1 == p) ? d : r1d;
      else nv1 = (c1 == p) ? (-colp[k] * d) : fma(-colp[k], r1d, aj[c1][r]);
      aj[c1][r] = nv1;
    }
    __syncthreads();
  }
  for (int idx = tid; idx < 64 * 64; idx += 256) {
    const int r = idx >> 6, c = idx & 63;
    Dinv[idx] = aj[c][r];
  }
}

// ---------------- stagefix: blocks 0-31 rowscale; blocks 32-543 colprep ----------------
#define DBM 64
#define DBK 8
__global__ __launch_bounds__(256)
void k_stagefix(const double* __restrict__ Dinv, double* __restrict__ M,
                double* __restrict__ Rpan, double* __restrict__ Cpan, int p)
{
  const int blk = blockIdx.x;
  const int tid = threadIdx.x;
  if (blk >= 32) {
    const int idx = (blk - 32) * 256 + tid;   // 2048*64 total
    const int i = idx >> 6, k = idx & 63;
    const bool inP = (i >> 6) == p;
    const size_t mo = (size_t)i * DIMN + p * 64 + k;
    double v = 0.0;
    if (!inP) { v = M[mo]; M[mo] = 0.0; }
    Cpan[idx] = v;
    return;
  }
  __shared__ double As[DBK][DBM];
  __shared__ double Bs[DBK][DBM];
  const double* Mrow = M + (size_t)p * 64 * DIMN;
  const int tx = tid & 15, ty = tid >> 4;
  const int bcol = blk * DBM;

  const int arow = tid >> 2, ac0 = (tid & 3) * 2;
  const int brw  = tid >> 5, bc0 = (tid & 31) * 2;

  const double* Aptr = Dinv + (size_t)arow * 64 + ac0;
  const double* Bptr = Mrow + (size_t)brw * DIMN + (bcol + bc0);

  double2 aPre = *(const double2*)Aptr;
  double2 bPre = *(const double2*)Bptr;

  double acc[4][4];
#pragma unroll
  for (int i = 0; i < 4; ++i)
#pragma unroll
    for (int j = 0; j < 4; ++j) acc[i][j] = 0.0;

  for (int kt = 0; kt < 8; ++kt) {
    As[ac0 + 0][arow] = aPre.x;
    As[ac0 + 1][arow] = aPre.y;
    Bs[brw][bc0 + 0] = bPre.x;
    Bs[brw][bc0 + 1] = bPre.y;
    __syncthreads();
    if (kt + 1 < 8) {
      aPre = *(const double2*)(Aptr + (size_t)(kt + 1) * DBK);
      bPre = *(const double2*)(Bptr + (size_t)(kt + 1) * DBK * DIMN);
    }
#pragma unroll
    for (int kk = 0; kk < DBK; ++kk) {
      double a[4], b[4];
#pragma unroll
      for (int i = 0; i < 4; ++i) a[i] = As[kk][ty * 4 + i];
#pragma unroll
      for (int j = 0; j < 4; ++j) b[j] = Bs[kk][tx * 4 + j];
#pragma unroll
      for (int i = 0; i < 4; ++i)
#pragma unroll
        for (int j = 0; j < 4; ++j)
          acc[i][j] = fma(a[i], b[j], acc[i][j]);
    }
    __syncthreads();
  }
  const bool pivcol = (bcol >> 6) == p;
#pragma unroll
  for (int i = 0; i < 4; ++i) {
    const int gi = ty * 4 + i;
#pragma unroll
    for (int j = 0; j < 4; ++j) {
      const int gj = bcol + tx * 4 + j;
      double v = pivcol ? Dinv[(size_t)gi * 64 + (gj & 63)] : acc[i][j];
      Rpan[(size_t)gi * DIMN + gj] = v;
      M[(size_t)(p * 64 + gi) * DIMN + gj] = v;
    }
  }
}

// ---------------- matvec f32 matrix, f64 vectors ----------------
__global__ __launch_bounds__(256)
void k_mv(const float* __restrict__ Mat, const double* __restrict__ vin,
          double* vout, const double* vadd, double alpha)
{
  const int lane = threadIdx.x & 63;
  const int row = blockIdx.x * 4 + (threadIdx.x >> 6);
  const float* mrow = Mat + (size_t)row * DIMN;
  double acc = 0.0;
  for (int p = 0; p < DIMN; p += 256) {
    const float4 m = *(const float4*)&mrow[p + lane * 4];
    const double* vp = &vin[p + lane * 4];
    acc += (double)m.x * vp[0] + (double)m.y * vp[1] + (double)m.z * vp[2] + (double)m.w * vp[3];
  }
  for (int off = 32; off; off >>= 1) acc += __shfl_down(acc, off);
  if (lane == 0) vout[row] = alpha * acc + (vadd ? vadd[row] : 0.0);
}

// ---------------- matvec f64 matrix ----------------
__global__ __launch_bounds__(256)
void k_mv64(const double* __restrict__ W, const double* __restrict__ vin,
            double* vout, const double* vadd, double alpha)
{
  const int lane = threadIdx.x & 63;
  const int row = blockIdx.x * 4 + (threadIdx.x >> 6);
  const double* mrow = W + (size_t)row * DIMN;
  double acc = 0.0;
  for (int p = 0; p < DIMN; p += 256) {
    const int idx = p + lane * 4;
    const double2 m0 = *(const double2*)&mrow[idx];
    const double2 m1 = *(const double2*)&mrow[idx + 2];
    acc += m0.x * vin[idx] + m0.y * vin[idx + 1] + m1.x * vin[idx + 2] + m1.y * vin[idx + 3];
  }
  for (int off = 32; off; off >>= 1) acc += __shfl_down(acc, off);
  if (lane == 0) vout[row] = alpha * acc + (vadd ? vadd[row] : 0.0);
}

// ---------------- residual: r = y - (A*x + 1e-3*x) ----------------
__global__ __launch_bounds__(256)
void k_mvres(const float* __restrict__ A, const double* __restrict__ x,
             const double* __restrict__ y, double* r)
{
  const int lane = threadIdx.x & 63;
  const int row = blockIdx.x * 4 + (threadIdx.x >> 6);
  const float* mrow = A + (size_t)row * DIMN;
  double acc = 0.0;
  for (int p = 0; p < DIMN; p += 256) {
    const float4 m = *(const float4*)&mrow[p + lane * 4];
    const double* vp = &x[p + lane * 4];
    acc += (double)m.x * vp[0] + (double)m.y * vp[1] + (double)m.z * vp[2] + (double)m.w * vp[3];
  }
  for (int off = 32; off; off >>= 1) acc += __shfl_down(acc, off);
  if (lane == 0) r[row] = y[row] - acc - 1e-3 * x[row];
}

// ---------------- transpose 2048x2048 f32 ----------------
__global__ __launch_bounds__(256)
void k_transpose(const float* __restrict__ in, float* __restrict__ out)
{
  __shared__ float t[32][33];
  const int bx = blockIdx.x * 32, by = blockIdx.y * 32;
  const int lx = threadIdx.x, ly = threadIdx.y;
  for (int dy = 0; dy < 32; dy += 8)
    t[ly + dy][lx] = in[(size_t)(by + ly + dy) * DIMN + bx + lx];
  __syncthreads();
  for (int dy = 0; dy < 32; dy += 8)
    out[(size_t)(bx + ly + dy) * DIMN + by + lx] = t[lx][ly + dy];
}

// ---------------- chain step (bootstrap): vout=(I+E)vin; uout=(I+ERT)uin ----------------
__global__ __launch_bounds__(256)
void k_chain(const float* __restrict__ E, const float* __restrict__ vin, float* __restrict__ vout,
             const float* __restrict__ ERT, const float* __restrict__ uin, float* __restrict__ uout)
{
  const int lane = threadIdx.x & 63;
  const int w = threadIdx.x >> 6;
  const int b = blockIdx.x;
  const float* mrow; const float* xin; float* xout; int row;
  if (b < 512) { row = b * 4 + w; mrow = E + (size_t)row * DIMN; xin = vin; xout = vout; }
  else { row = (b - 512) * 4 + w; mrow = ERT + (size_t)row * DIMN; xin = uin; xout = uout; }
  float acc = 0.f;
  for (int p = 0; p < DIMN; p += 256) {
    const float4 m = *(const float4*)&mrow[p + lane * 4];
    const float* vp = &xin[p + lane * 4];
    acc = fmaf(m.x, vp[0], acc);
    acc = fmaf(m.y, vp[1], acc);
    acc = fmaf(m.z, vp[2], acc);
    acc = fmaf(m.w, vp[3], acc);
  }
  for (int off = 32; off; off >>= 1) acc += __shfl_down(acc, off);
  if (lane == 0) xout[row] = xin[row] + acc;
}

// ---------------- batched chain: 8 V-steps (E8) + 4 U-steps (ER4T) per launch ----------------
__global__ __launch_bounds__(256)
void k_chainb(const float* __restrict__ E8, const float* __restrict__ Vin,
              float* __restrict__ Vout, int do_v,
              const float* __restrict__ A4T, const float* __restrict__ Uin,
              float* __restrict__ Uout)
{
  const int lane = threadIdx.x & 63;
  const int w = threadIdx.x >> 6;
  const int b = blockIdx.x;
  if (b < 512) {
    if (!do_v) return;
    const int row = b * 4 + w;
    const float* mrow = E8 + (size_t)row * DIMN;
    float acc[8];
#pragma unroll
    for (int r = 0; r < 8; ++r) acc[r] = 0.f;
    for (int p = 0; p < DIMN; p += 256) {
      const float4 m = *(const float4*)&mrow[p + lane * 4];
#pragma unroll
      for (int r = 0; r < 8; ++r) {
        const float4 v = *(const float4*)&Vin[(size_t)r * DIMN + p + lane * 4];
        acc[r] = fmaf(m.x, v.x, acc[r]);
        acc[r] = fmaf(m.y, v.y, acc[r]);
        acc[r] = fmaf(m.z, v.z, acc[r]);
        acc[r] = fmaf(m.w, v.w, acc[r]);
      }
    }
#pragma unroll
    for (int r = 0; r < 8; ++r) {
      float a = acc[r];
      for (int off = 32; off; off >>= 1) a += __shfl_down(a, off);
      if (lane == 0) Vout[(size_t)r * DIMN + row] = Vin[(size_t)r * DIMN + row] + a;
    }
  } else {
    const int row = (b - 512) * 4 + w;
    const float* mrow = A4T + (size_t)row * DIMN;
    float acc[4];
#pragma unroll
    for (int r = 0; r < 4; ++r) acc[r] = 0.f;
    for (int p = 0; p < DIMN; p += 256) {
      const float4 m = *(const float4*)&mrow[p + lane * 4];
#pragma unroll
      for (int r = 0; r < 4; ++r) {
        const float4 v = *(const float4*)&Uin[(size_t)r * DIMN + p + lane * 4];
        acc[r] = fmaf(m.x, v.x, acc[r]);
        acc[r] = fmaf(m.y, v.y, acc[r]);
        acc[r] = fmaf(m.z, v.z, acc[r]);
        acc[r] = fmaf(m.w, v.w, acc[r]);
      }
    }
#pragma unroll
    for (int r = 0; r < 4; ++r) {
      float a = acc[r];
      for (int off = 32; off; off >>= 1) a += __shfl_down(a, off);
      if (lane == 0) Uout[(size_t)r * DIMN + row] = Uin[(size_t)r * DIMN + row] + a;
    }
  }
}

// ---------------- terms: out[8191-t] = dot(U[t/91], V[t%91]) ----------------
__global__ __launch_bounds__(256)
void k_terms(const float* __restrict__ U, const float* __restrict__ V, float* __restrict__ out)
{
  const int lane = threadIdx.x & 63;
  const int t = blockIdx.x * 4 + (threadIdx.x >> 6);
  const int j = t / RSPLIT, i = t - j * RSPLIT;
  const float* u = U + (size_t)j * DIMN;
  const float* v = V + (size_t)i * DIMN;
  float acc = 0.f;
  for (int p = 0; p < DIMN; p += 256) {
    const float4 a4 = *(const float4*)&u[p + lane * 4];
    const float4 b4 = *(const float4*)&v[p + lane * 4];
    acc = fmaf(a4.x, b4.x, acc); acc = fmaf(a4.y, b4.y, acc);
    acc = fmaf(a4.z, b4.z, acc); acc = fmaf(a4.w, b4.w, acc);
  }
  for (int off = 32; off; off >>= 1) acc += __shfl_down(acc, off);
  if (lane == 0) out[MSTEPS - 1 - t] = acc;
}

// ---------------- small vector inits ----------------
__global__ void k_vecinit(const float* __restrict__ B, double* __restrict__ b64,
                          const float* __restrict__ Cv, float* __restrict__ U0)
{
  const int i = blockIdx.x * 256 + threadIdx.x;
  if (i < DIMN) { b64[i] = 0.01 * (double)B[i]; U0[i] = Cv[i]; }
}
__global__ void k_v0(const double* __restrict__ x64, float* __restrict__ V0)
{
  const int i = blockIdx.x * 256 + threadIdx.x;
  if (i < DIMN) V0[i] = (float)x64[i];
}

extern "C" void kernel_launch(void* const* d_in, const int* in_sizes, int n_in,
                              void* d_out, int out_size, void* d_ws, size_t ws_size,
                              hipStream_t stream)
{
  const float* dA = (const float*)d_in[0];
  const float* dB = (const float*)d_in[1];
  const float* dC = (const float*)d_in[2];
  float* out = (float*)d_out;

  float* fb = (float*)d_ws;
  float* Ebuf = fb;                 // E (f32, written by Y2-gemm epilogue; bootstrap V)
  float* t1 = fb + NN;              // M64 lo -> Y2 splits -> E8 (f32, batch V)
  float* t2 = t1 + NN;              // M64 hi -> Hth/Htl splits
  float* t3 = t2 + NN;              // Y2 (f32) -> ER4T (f32, batch U)
  float* t4 = t3 + NN;              // Ah/Al (bf16) -> ER -> ER4
  float* t5 = t4 + NN;              // Ath/Atl (bf16) -> ERT (f32, bootstrap U)
  double* M64 = (double*)t1;        // spans t1,t2
  double* scr64 = (double*)(fb + 6 * NN);
  double* Dinv = scr64;                        // 64x64
  double* Cpan = Dinv + 64 * 64;               // 2048x64
  double* Rpan = Cpan + (size_t)DIMN * 64;     // 64x2048
  double* y64 = Rpan + (size_t)DIMN * 64;
  double* x64 = y64 + DIMN;
  double* r64 = x64 + DIMN;
  double* b64 = r64 + DIMN;
  float* V  = (float*)(b64 + DIMN);            // 96 x 2048
  float* Uc = V + (size_t)96 * DIMN;           // 92 x 2048

  const size_t needed = 6 * NN * 4
                        + (64 * 64 + 2 * (size_t)DIMN * 64 + 4 * (size_t)DIMN) * 8
                        + (size_t)(96 + 92) * DIMN * 4;
  if (ws_size < needed) return;

  const float* NUL = nullptr;
  float* NULo = nullptr;
  dim3 cb(256), cg(2048);

  unsigned short* Ah  = (unsigned short*)t4;   unsigned short* Al  = Ah + NN;
  unsigned short* Ath = (unsigned short*)t5;   unsigned short* Atl = Ath + NN;
  unsigned short* Y2h = (unsigned short*)t1;   unsigned short* Y2l = Y2h + NN;
  unsigned short* Hth = (unsigned short*)t2;   unsigned short* Htl = Hth + NN;

  // ---- Phase 0: bf16 splits of A; Y2 = 0.8281*A^2 with fused E epilogue ----
  k_splitboth<<<dim3(64, 64), dim3(32, 8), 0, stream>>>(dA, Ah, Al, Ath, Atl);
  k_gemm3<<<dim3(16, 16), cb, 0, stream>>>(Ah, Al, Ath, Atl, t3, 0.8281f,
                                           NUL, 0.f, NUL, 0.f,
                                           dA, Ebuf, (float)(5e-5 / 0.8281), 0.01f); // Y2 + E

  // ---- Phase 1: M64 = A + 1e-3 I; flat blocked GJ (stagefix + fused ftrail/Jordan) ----
  k_fill64<<<cg, cb, 0, stream>>>(dA, M64);
  k_gj64<<<dim3(1), cb, 0, stream>>>(M64, DIMN, Dinv, 64);     // stage-0 pivot inverse
  for (int s = 0; s < NBLK; ++s) {
    k_stagefix<<<dim3(544), cb, 0, stream>>>(Dinv, M64, Rpan, Cpan, s);
    k_ftrail<<<dim3(32, 32), cb, 0, stream>>>(Cpan, Rpan, M64, Dinv, s + 1,
                                              (s < NBLK - 1) ? 1 : 0);
  }

  // ---- Phase 3: Bbar: y = E*(0.01B); x = W*y; 1x f64 IR ----
  k_vecinit<<<dim3(8), cb, 0, stream>>>(dB, b64, dC, Uc);
  k_mv<<<dim3(512), cb, 0, stream>>>(Ebuf, b64, y64, (const double*)nullptr, 1.0);
  k_mv64<<<dim3(512), cb, 0, stream>>>(M64, y64, x64, (const double*)nullptr, 1.0);
  k_mvres<<<dim3(512), cb, 0, stream>>>(dA, x64, y64, r64);
  k_mv64<<<dim3(512), cb, 0, stream>>>(M64, r64, x64, x64, 1.0);
  k_v0<<<dim3(8), cb, 0, stream>>>(x64, V);                                     // V[0] = Bbar

  // ---- Phase 4: ER, ER4 (bf16x3 GEMMs), E8 (elementwise), transposes ----
  k_split<<<dim3(4096), cb, 0, stream>>>(t3, Y2h, Y2l);                         // W dead
  k_combsplitT<<<dim3(64, 64), dim3(32, 8), 0, stream>>>(dA, 0.91f / 6.f,
                                                         t3, 1.f / 24.f, Hth, Htl);
  k_gemm3<<<dim3(16, 16), cb, 0, stream>>>(Y2h, Y2l, Hth, Htl, t4, 1.f,
                                           t3, 0.5f, dA, 0.91f,
                                           NUL, NULo, 0.f, 0.f);                // ER -> t4
  k_transpose<<<dim3(64, 64), dim3(32, 8), 0, stream>>>(t4, t5);                // ERT -> t5
  k_combsplitT<<<dim3(64, 64), dim3(32, 8), 0, stream>>>(dA, 3.64f / 6.f,
                                                         t3, 16.f / 24.f, Hth, Htl);
  k_gemm3<<<dim3(16, 16), cb, 0, stream>>>(Y2h, Y2l, Hth, Htl, t4, 16.f,
                                           t3, 8.f, dA, 3.64f,
                                           NUL, NULo, 0.f, 0.f);                // ER4 -> t4
  k_combine4<<<cg, cb, 0, stream>>>(t1, dA, 0.08f, t3, (float)(0.0032 / 0.8281),
                                    NUL, 0, NUL, 0, 0.f);                       // E8 -> t1
  k_transpose<<<dim3(64, 64), dim3(32, 8), 0, stream>>>(t4, t3);                // ER4T -> t3

  // ---- Phase 5: bootstrap (7 serial) + 22 batched launches + terms ----
  for (int s = 0; s < 7; ++s) {
    k_chain<<<dim3(1024), cb, 0, stream>>>(Ebuf, V + (size_t)s * DIMN, V + (size_t)(s + 1) * DIMN,
                                           t5, Uc + (size_t)s * DIMN, Uc + (size_t)(s + 1) * DIMN);
  }
  for (int i = 0; i < 22; ++i) {
    k_chainb<<<dim3(1024), cb, 0, stream>>>(
        t1, V + (size_t)(8 * i) * DIMN, V + (size_t)(8 * i + 8) * DIMN, (i < 11) ? 1 : 0,
        t3, Uc + (size_t)(4 * i) * DIMN, Uc + (size_t)(4 * i + 4) * DIMN);
  }
  k_terms<<<dim3(2048), cb, 0, stream>>>(Uc, V, out);
}

// Round 16
// 4188.649 us; speedup vs baseline: 1.0564x; 1.0192x over previous
//
#include <hip/hip_runtime.h>
#include <hip/hip_bf16.h>

// ZOH linear layer: K[1,8192], dim 2048.
// Y2=(0.91A)^2, ER via bf16x3-split MFMA GEMMs; E elementwise from Y2.
// W=inv(A+1e-3 I) f64 in-place flat blocked GJ (gj64 v6 unpivoted col-major,
// stagefix, 64-tile trailing f64 GEMM) + 1 f64 IR step on the solve vector.
// K[91j+i] = (C*AR^j)·(A^i*Bbar): two balanced serial matvec chains (90 steps) + dots.
// (Round-10 configuration: best-known-good at 4.203 ms.)

#define DIMN 2048
#define MSTEPS 8192
#define RSPLIT 91
#define NSTEPS 90
#define NN ((size_t)DIMN * DIMN)
#define NBLK 32
#define ALD 40   // LDS pitch (bf16) for gemm3 tiles
#define GJP 65   // gj64 panel pitch (f64), odd -> bank-friendly

typedef short short8 __attribute__((ext_vector_type(8)));
typedef float f32x4 __attribute__((ext_vector_type(4)));

__device__ inline void split1(float x, unsigned short& h, unsigned short& l)
{
  __hip_bfloat16 b = __float2bfloat16(x);
  h = *reinterpret_cast<unsigned short*>(&b);
  float r = x - __bfloat162float(b);
  __hip_bfloat16 b2 = __float2bfloat16(r);
  l = *reinterpret_cast<unsigned short*>(&b2);
}

// ---------------- elementwise f32: out = c1*i1+c2*i2 + dval*I ----------------
__global__ __launch_bounds__(256)
void k_combine4(float* out,
                const float* i1, float c1, const float* i2, float c2,
                const float* i3, float c3, const float* i4, float c4,
                float dval)
{
  const int total = DIMN * DIMN;
  for (int idx = blockIdx.x * 256 + threadIdx.x; idx < total; idx += gridDim.x * 256) {
    float v = 0.f;
    if (i1) v = fmaf(c1, i1[idx], v);
    if (i2) v = fmaf(c2, i2[idx], v);
    if (i3) v = fmaf(c3, i3[idx], v);
    if (i4) v = fmaf(c4, i4[idx], v);
    if ((idx >> 11) == (idx & 2047)) v += dval;
    out[idx] = v;
  }
}

// ---------------- M64 = (double)A + 1e-3 I ----------------
__global__ __launch_bounds__(256)
void k_fill64(const float* __restrict__ A, double* __restrict__ M)
{
  const int total = DIMN * DIMN;
  for (int idx = blockIdx.x * 256 + threadIdx.x; idx < total; idx += gridDim.x * 256) {
    double v = (double)A[idx];
    if ((idx >> 11) == (idx & 2047)) v += 1e-3;
    M[idx] = v;
  }
}

// ---------------- split f32 -> bf16 hi/lo (linear) ----------------
__global__ __launch_bounds__(256)
void k_split(const float* __restrict__ in, unsigned short* __restrict__ hi,
             unsigned short* __restrict__ lo)
{
  const int i4 = blockIdx.x * 256 + threadIdx.x;   // grid 4096: NN/4 float4s
  const float4 v = ((const float4*)in)[i4];
  ushort4 h, l;
  split1(v.x, h.x, l.x); split1(v.y, h.y, l.y);
  split1(v.z, h.z, l.z); split1(v.w, h.w, l.w);
  ((ushort4*)hi)[i4] = h;
  ((ushort4*)lo)[i4] = l;
}

// ---------------- split f32 -> bf16 hi/lo, transposed output [n][k] ----------------
__global__ __launch_bounds__(256)
void k_splitT(const float* __restrict__ in, unsigned short* __restrict__ hi,
              unsigned short* __restrict__ lo)
{
  __shared__ float t[32][33];
  const int bx = blockIdx.x * 32, by = blockIdx.y * 32;
  const int lx = threadIdx.x, ly = threadIdx.y; // (32,8)
  for (int dy = 0; dy < 32; dy += 8)
    t[ly + dy][lx] = in[(size_t)(by + ly + dy) * DIMN + bx + lx];
  __syncthreads();
  for (int dy = 0; dy < 32; dy += 8) {
    const size_t o = (size_t)(bx + ly + dy) * DIMN + by + lx;
    unsigned short h, l;
    split1(t[lx][ly + dy], h, l);
    hi[o] = h; lo[o] = l;
  }
}

// ---------------- bf16x3 MFMA GEMM: C = alpha*(A*B) + c1*E1 + c2*E2 ----------------
__global__ __launch_bounds__(256)
void k_gemm3(const unsigned short* __restrict__ Ahg, const unsigned short* __restrict__ Alg,
             const unsigned short* __restrict__ Bhg, const unsigned short* __restrict__ Blg,
             float* __restrict__ C, float alpha,
             const float* E1, float c1, const float* E2, float c2)
{
  __shared__ unsigned short sAh[128 * ALD];
  __shared__ unsigned short sAl[128 * ALD];
  __shared__ unsigned short sBh[128 * ALD];
  __shared__ unsigned short sBl[128 * ALD];
  const int tid = threadIdx.x;
  const int wid = tid >> 6, lane = tid & 63;
  const int lr = lane & 15, lg = lane >> 4;
  const int wm = wid >> 1, wn = wid & 1;
  const int brow = blockIdx.y * 128, bcol = blockIdx.x * 128;
  const int sr = tid >> 1, sh = (tid & 1) * 16;

  const unsigned short* gAh = Ahg + (size_t)(brow + sr) * DIMN + sh;
  const unsigned short* gAl = Alg + (size_t)(brow + sr) * DIMN + sh;
  const unsigned short* gBh = Bhg + (size_t)(bcol + sr) * DIMN + sh;
  const unsigned short* gBl = Blg + (size_t)(bcol + sr) * DIMN + sh;

  f32x4 acc[4][4];
#pragma unroll
  for (int mf = 0; mf < 4; ++mf)
#pragma unroll
    for (int nf = 0; nf < 4; ++nf) acc[mf][nf] = (f32x4){0.f, 0.f, 0.f, 0.f};

  uint4 pa0 = *(const uint4*)gAh;      uint4 pa1 = *(const uint4*)(gAh + 8);
  uint4 pb0 = *(const uint4*)gAl;      uint4 pb1 = *(const uint4*)(gAl + 8);
  uint4 pc0 = *(const uint4*)gBh;      uint4 pc1 = *(const uint4*)(gBh + 8);
  uint4 pd0 = *(const uint4*)gBl;      uint4 pd1 = *(const uint4*)(gBl + 8);

  const int nk = DIMN / 32;
  for (int kt = 0; kt < nk; ++kt) {
    *(uint4*)&sAh[sr * ALD + sh] = pa0;  *(uint4*)&sAh[sr * ALD + sh + 8] = pa1;
    *(uint4*)&sAl[sr * ALD + sh] = pb0;  *(uint4*)&sAl[sr * ALD + sh + 8] = pb1;
    *(uint4*)&sBh[sr * ALD + sh] = pc0;  *(uint4*)&sBh[sr * ALD + sh + 8] = pc1;
    *(uint4*)&sBl[sr * ALD + sh] = pd0;  *(uint4*)&sBl[sr * ALD + sh + 8] = pd1;
    __syncthreads();
    if (kt + 1 < nk) {
      const int o = (kt + 1) * 32;
      pa0 = *(const uint4*)(gAh + o);  pa1 = *(const uint4*)(gAh + o + 8);
      pb0 = *(const uint4*)(gAl + o);  pb1 = *(const uint4*)(gAl + o + 8);
      pc0 = *(const uint4*)(gBh + o);  pc1 = *(const uint4*)(gBh + o + 8);
      pd0 = *(const uint4*)(gBl + o);  pd1 = *(const uint4*)(gBl + o + 8);
    }
#pragma unroll
    for (int mf = 0; mf < 4; ++mf) {
      const int ar = 64 * wm + 16 * mf + lr;
      const short8 ah = *(const short8*)&sAh[ar * ALD + lg * 8];
      const short8 al = *(const short8*)&sAl[ar * ALD + lg * 8];
#pragma unroll
      for (int nf = 0; nf < 4; ++nf) {
        const int br = 64 * wn + 16 * nf + lr;
        const short8 bh = *(const short8*)&sBh[br * ALD + lg * 8];
        const short8 bl = *(const short8*)&sBl[br * ALD + lg * 8];
        acc[mf][nf] = __builtin_amdgcn_mfma_f32_16x16x32_bf16(ah, bh, acc[mf][nf], 0, 0, 0);
        acc[mf][nf] = __builtin_amdgcn_mfma_f32_16x16x32_bf16(ah, bl, acc[mf][nf], 0, 0, 0);
        acc[mf][nf] = __builtin_amdgcn_mfma_f32_16x16x32_bf16(al, bh, acc[mf][nf], 0, 0, 0);
      }
    }
    __syncthreads();
  }
#pragma unroll
  for (int mf = 0; mf < 4; ++mf) {
#pragma unroll
    for (int nf = 0; nf < 4; ++nf) {
      const int col = bcol + 64 * wn + 16 * nf + lr;
#pragma unroll
      for (int i = 0; i < 4; ++i) {
        const int row = brow + 64 * wm + 16 * mf + 4 * lg + i;
        float v = alpha * acc[mf][nf][i];
        if (E1) v = fmaf(c1, E1[(size_t)row * DIMN + col], v);
        if (E2) v = fmaf(c2, E2[(size_t)row * DIMN + col], v);
        C[(size_t)row * DIMN + col] = v;
      }
    }
  }
}

// ---------------- f64 GEMM (VALU): C = alpha*A*B + c1*E1 (64x64 tile) ----------------
#define DBM 64
#define DBK 8
__global__ __launch_bounds__(256)
void k_dgemm(const double* __restrict__ A, int lda,
             const double* __restrict__ B, int ldb,
             double* C, int ldc, int K, double alpha,
             const double* E1, int ld1, double c1)
{
  __shared__ double As[DBK][DBM];
  __shared__ double Bs[DBK][DBM];
  const int tid = threadIdx.x;
  const int tx = tid & 15, ty = tid >> 4;
  const int brow = blockIdx.y * DBM, bcol = blockIdx.x * DBM;

  const int arow = tid >> 2, ac0 = (tid & 3) * 2;
  const int brw  = tid >> 5, bc0 = (tid & 31) * 2;

  const double* Aptr = A + (size_t)(brow + arow) * lda + ac0;
  const double* Bptr = B + (size_t)brw * ldb + (bcol + bc0);

  double2 aPre = *(const double2*)Aptr;
  double2 bPre = *(const double2*)Bptr;

  double acc[4][4];
#pragma unroll
  for (int i = 0; i < 4; ++i)
#pragma unroll
    for (int j = 0; j < 4; ++j) acc[i][j] = 0.0;

  const int nk = K / DBK;
  for (int kt = 0; kt < nk; ++kt) {
    As[ac0 + 0][arow] = aPre.x;
    As[ac0 + 1][arow] = aPre.y;
    Bs[brw][bc0 + 0] = bPre.x;
    Bs[brw][bc0 + 1] = bPre.y;
    __syncthreads();
    if (kt + 1 < nk) {
      aPre = *(const double2*)(Aptr + (size_t)(kt + 1) * DBK);
      bPre = *(const double2*)(Bptr + (size_t)(kt + 1) * DBK * ldb);
    }
#pragma unroll
    for (int kk = 0; kk < DBK; ++kk) {
      double a[4], b[4];
#pragma unroll
      for (int i = 0; i < 4; ++i) a[i] = As[kk][ty * 4 + i];
#pragma unroll
      for (int j = 0; j < 4; ++j) b[j] = Bs[kk][tx * 4 + j];
#pragma unroll
      for (int i = 0; i < 4; ++i)
#pragma unroll
        for (int j = 0; j < 4; ++j)
          acc[i][j] = fma(a[i], b[j], acc[i][j]);
    }
    __syncthreads();
  }
#pragma unroll
  for (int i = 0; i < 4; ++i) {
    const int gi = brow + ty * 4 + i;
#pragma unroll
    for (int j = 0; j < 4; ++j) {
      const int gj = bcol + tx * 4 + j;
      double v = alpha * acc[i][j];
      if (E1) v = fma(c1, E1[(size_t)gi * ld1 + gj], v);
      C[(size_t)gi * ldc + gj] = v;
    }
  }
}

// ---------------- gj64 v6: UNPIVOTED 64x64 f64 GJ, col-major LDS panel ----------------
__global__ __launch_bounds__(256)
void k_gj64(const double* __restrict__ M, int ldm, double* __restrict__ W, int ldw)
{
  __shared__ double a[128][GJP];   // a[c][r] = P[r][c]; [A | I] col-major
  const int tid = threadIdx.x;
  const int rg = tid & 7;          // rows [8rg, 8rg+8)
  const int cg = tid >> 3;         // 0..31

  for (int idx = tid; idx < 64 * 64; idx += 256) {
    const int r = idx >> 6, c = idx & 63;
    a[c][r] = M[(size_t)r * ldm + c];
    a[64 + c][r] = (r == c) ? 1.0 : 0.0;
  }
  __syncthreads();

  for (int p = 0; p < 64; ++p) {
    const double rpv = 1.0 / a[p][p];
    const int c0 = p + 1 + cg;
    const int c1 = c0 + 32;
    const double prs0 = a[c0][p] * rpv;
    const double prs1 = a[c1][p] * rpv;
    double colp[8];
#pragma unroll
    for (int k = 0; k < 4; ++k) {
      const double2 t2 = *(const double2*)&a[p][rg * 8 + 2 * k];
      colp[2 * k] = t2.x; colp[2 * k + 1] = t2.y;
    }
    __syncthreads();
#pragma unroll
    for (int k = 0; k < 8; ++k) {
      const int r = rg * 8 + k;
      const bool isp = (r == p);
      const double v0 = a[c0][r];
      const double v1 = a[c1][r];
      a[c0][r] = isp ? prs0 : fma(-colp[k], prs0, v0);
      a[c1][r] = isp ? prs1 : fma(-colp[k], prs1, v1);
    }
    __syncthreads();
  }

  for (int idx = tid; idx < 64 * 64; idx += 256) {
    const int r = idx >> 6, c = idx & 63;
    W[(size_t)r * ldw + c] = a[64 + c][r];
  }
}

// ---------------- stagefix: blocks 0-31 rowscale; blocks 32-543 colprep ----------------
__global__ __launch_bounds__(256)
void k_stagefix(const double* __restrict__ Dinv, double* __restrict__ M,
                double* __restrict__ Rpan, double* __restrict__ Cpan, int p)
{
  const int blk = blockIdx.x;
  const int tid = threadIdx.x;
  if (blk >= 32) {
    const int idx = (blk - 32) * 256 + tid;   // 2048*64 total
    const int i = idx >> 6, k = idx & 63;
    const bool inP = (i >> 6) == p;
    const size_t mo = (size_t)i * DIMN + p * 64 + k;
    double v = 0.0;
    if (!inP) { v = M[mo]; M[mo] = 0.0; }
    Cpan[idx] = v;
    return;
  }
  __shared__ double As[DBK][DBM];
  __shared__ double Bs[DBK][DBM];
  const double* Mrow = M + (size_t)p * 64 * DIMN;
  const int tx = tid & 15, ty = tid >> 4;
  const int bcol = blk * DBM;

  const int arow = tid >> 2, ac0 = (tid & 3) * 2;
  const int brw  = tid >> 5, bc0 = (tid & 31) * 2;

  const double* Aptr = Dinv + (size_t)arow * 64 + ac0;
  const double* Bptr = Mrow + (size_t)brw * DIMN + (bcol + bc0);

  double2 aPre = *(const double2*)Aptr;
  double2 bPre = *(const double2*)Bptr;

  double acc[4][4];
#pragma unroll
  for (int i = 0; i < 4; ++i)
#pragma unroll
    for (int j = 0; j < 4; ++j) acc[i][j] = 0.0;

  for (int kt = 0; kt < 8; ++kt) {
    As[ac0 + 0][arow] = aPre.x;
    As[ac0 + 1][arow] = aPre.y;
    Bs[brw][bc0 + 0] = bPre.x;
    Bs[brw][bc0 + 1] = bPre.y;
    __syncthreads();
    if (kt + 1 < 8) {
      aPre = *(const double2*)(Aptr + (size_t)(kt + 1) * DBK);
      bPre = *(const double2*)(Bptr + (size_t)(kt + 1) * DBK * DIMN);
    }
#pragma unroll
    for (int kk = 0; kk < DBK; ++kk) {
      double a[4], b[4];
#pragma unroll
      for (int i = 0; i < 4; ++i) a[i] = As[kk][ty * 4 + i];
#pragma unroll
      for (int j = 0; j < 4; ++j) b[j] = Bs[kk][tx * 4 + j];
#pragma unroll
      for (int i = 0; i < 4; ++i)
#pragma unroll
        for (int j = 0; j < 4; ++j)
          acc[i][j] = fma(a[i], b[j], acc[i][j]);
    }
    __syncthreads();
  }
  const bool pivcol = (bcol >> 6) == p;
#pragma unroll
  for (int i = 0; i < 4; ++i) {
    const int gi = ty * 4 + i;
#pragma unroll
    for (int j = 0; j < 4; ++j) {
      const int gj = bcol + tx * 4 + j;
      double v = pivcol ? Dinv[(size_t)gi * 64 + (gj & 63)] : acc[i][j];
      Rpan[(size_t)gi * DIMN + gj] = v;
      M[(size_t)(p * 64 + gi) * DIMN + gj] = v;
    }
  }
}

// ---------------- matvec f32 matrix, f64 vectors ----------------
__global__ __launch_bounds__(256)
void k_mv(const float* __restrict__ Mat, const double* __restrict__ vin,
          double* vout, const double* vadd, double alpha)
{
  const int lane = threadIdx.x & 63;
  const int row = blockIdx.x * 4 + (threadIdx.x >> 6);
  const float* mrow = Mat + (size_t)row * DIMN;
  double acc = 0.0;
  for (int p = 0; p < DIMN; p += 256) {
    const float4 m = *(const float4*)&mrow[p + lane * 4];
    const double* vp = &vin[p + lane * 4];
    acc += (double)m.x * vp[0] + (double)m.y * vp[1] + (double)m.z * vp[2] + (double)m.w * vp[3];
  }
  for (int off = 32; off; off >>= 1) acc += __shfl_down(acc, off);
  if (lane == 0) vout[row] = alpha * acc + (vadd ? vadd[row] : 0.0);
}

// ---------------- matvec f64 matrix ----------------
__global__ __launch_bounds__(256)
void k_mv64(const double* __restrict__ W, const double* __restrict__ vin,
            double* vout, const double* vadd, double alpha)
{
  const int lane = threadIdx.x & 63;
  const int row = blockIdx.x * 4 + (threadIdx.x >> 6);
  const double* mrow = W + (size_t)row * DIMN;
  double acc = 0.0;
  for (int p = 0; p < DIMN; p += 256) {
    const int idx = p + lane * 4;
    const double2 m0 = *(const double2*)&mrow[idx];
    const double2 m1 = *(const double2*)&mrow[idx + 2];
    acc += m0.x * vin[idx] + m0.y * vin[idx + 1] + m1.x * vin[idx + 2] + m1.y * vin[idx + 3];
  }
  for (int off = 32; off; off >>= 1) acc += __shfl_down(acc, off);
  if (lane == 0) vout[row] = alpha * acc + (vadd ? vadd[row] : 0.0);
}

// ---------------- residual: r = y - (A*x + 1e-3*x) ----------------
__global__ __launch_bounds__(256)
void k_mvres(const float* __restrict__ A, const double* __restrict__ x,
             const double* __restrict__ y, double* r)
{
  const int lane = threadIdx.x & 63;
  const int row = blockIdx.x * 4 + (threadIdx.x >> 6);
  const float* mrow = A + (size_t)row * DIMN;
  double acc = 0.0;
  for (int p = 0; p < DIMN; p += 256) {
    const float4 m = *(const float4*)&mrow[p + lane * 4];
    const double* vp = &x[p + lane * 4];
    acc += (double)m.x * vp[0] + (double)m.y * vp[1] + (double)m.z * vp[2] + (double)m.w * vp[3];
  }
  for (int off = 32; off; off >>= 1) acc += __shfl_down(acc, off);
  if (lane == 0) r[row] = y[row] - acc - 1e-3 * x[row];
}

// ---------------- transpose 2048x2048 f32 ----------------
__global__ __launch_bounds__(256)
void k_transpose(const float* __restrict__ in, float* __restrict__ out)
{
  __shared__ float t[32][33];
  const int bx = blockIdx.x * 32, by = blockIdx.y * 32;
  const int lx = threadIdx.x, ly = threadIdx.y;
  for (int dy = 0; dy < 32; dy += 8)
    t[ly + dy][lx] = in[(size_t)(by + ly + dy) * DIMN + bx + lx];
  __syncthreads();
  for (int dy = 0; dy < 32; dy += 8)
    out[(size_t)(bx + ly + dy) * DIMN + by + lx] = t[lx][ly + dy];
}

// ---------------- chain step: vout=(I+E)vin (b<512); uout=(I+ERT)uin (b>=512) ----------------
__global__ __launch_bounds__(256)
void k_chain(const float* __restrict__ E, const float* __restrict__ vin, float* __restrict__ vout,
             const float* __restrict__ ERT, const float* __restrict__ uin, float* __restrict__ uout)
{
  const int lane = threadIdx.x & 63;
  const int w = threadIdx.x >> 6;
  const int b = blockIdx.x;
  const float* mrow; const float* xin; float* xout; int row;
  if (b < 512) { row = b * 4 + w; mrow = E + (size_t)row * DIMN; xin = vin; xout = vout; }
  else { row = (b - 512) * 4 + w; mrow = ERT + (size_t)row * DIMN; xin = uin; xout = uout; }
  float acc = 0.f;
  for (int p = 0; p < DIMN; p += 256) {
    const float4 m = *(const float4*)&mrow[p + lane * 4];
    const float* vp = &xin[p + lane * 4];
    acc = fmaf(m.x, vp[0], acc);
    acc = fmaf(m.y, vp[1], acc);
    acc = fmaf(m.z, vp[2], acc);
    acc = fmaf(m.w, vp[3], acc);
  }
  for (int off = 32; off; off >>= 1) acc += __shfl_down(acc, off);
  if (lane == 0) xout[row] = xin[row] + acc;
}

// ---------------- terms: out[8191-t] = dot(U[t/91], V[t%91]) ----------------
__global__ __launch_bounds__(256)
void k_terms(const float* __restrict__ U, const float* __restrict__ V, float* __restrict__ out)
{
  const int lane = threadIdx.x & 63;
  const int t = blockIdx.x * 4 + (threadIdx.x >> 6);
  const int j = t / RSPLIT, i = t - j * RSPLIT;
  const float* u = U + (size_t)j * DIMN;
  const float* v = V + (size_t)i * DIMN;
  float acc = 0.f;
  for (int p = 0; p < DIMN; p += 256) {
    const float4 a4 = *(const float4*)&u[p + lane * 4];
    const float4 b4 = *(const float4*)&v[p + lane * 4];
    acc = fmaf(a4.x, b4.x, acc); acc = fmaf(a4.y, b4.y, acc);
    acc = fmaf(a4.z, b4.z, acc); acc = fmaf(a4.w, b4.w, acc);
  }
  for (int off = 32; off; off >>= 1) acc += __shfl_down(acc, off);
  if (lane == 0) out[MSTEPS - 1 - t] = acc;
}

// ---------------- small vector inits ----------------
__global__ void k_vecinit(const float* __restrict__ B, double* __restrict__ b64,
                          const float* __restrict__ Cv, float* __restrict__ U0)
{
  const int i = blockIdx.x * 256 + threadIdx.x;
  if (i < DIMN) { b64[i] = 0.01 * (double)B[i]; U0[i] = Cv[i]; }
}
__global__ void k_v0(const double* __restrict__ x64, float* __restrict__ V0)
{
  const int i = blockIdx.x * 256 + threadIdx.x;
  if (i < DIMN) V0[i] = (float)x64[i];
}

extern "C" void kernel_launch(void* const* d_in, const int* in_sizes, int n_in,
                              void* d_out, int out_size, void* d_ws, size_t ws_size,
                              hipStream_t stream)
{
  const float* dA = (const float*)d_in[0];
  const float* dB = (const float*)d_in[1];
  const float* dC = (const float*)d_in[2];
  float* out = (float*)d_out;

  float* fb = (float*)d_ws;
  float* Ebuf = fb;                 // phase0: Ath/Atl (bf16); then E (f32, persistent)
  float* t1 = fb + NN;              // M64 lo / W lo; then Y2h/Y2l (bf16)
  float* t2 = t1 + NN;              // M64 hi / W hi; then Hth/Htl (bf16)
  float* t3 = t2 + NN;              // Y2 (f32) -> ER (f32, in-place epilogue)
  float* t4 = t3 + NN;              // Ah/Al (bf16); then H (f32); then ERT (f32)
  double* M64 = (double*)t1;        // spans t1,t2
  double* scr64 = (double*)(fb + 5 * NN);
  double* Dinv = scr64;                        // 64x64
  double* Cpan = Dinv + 64 * 64;               // 2048x64
  double* Rpan = Cpan + (size_t)DIMN * 64;     // 64x2048
  double* y64 = Rpan + (size_t)DIMN * 64;
  double* x64 = y64 + DIMN;
  double* r64 = x64 + DIMN;
  double* b64 = r64 + DIMN;
  float* V  = (float*)(b64 + DIMN);            // 91 x 2048
  float* Uc = V + (size_t)RSPLIT * DIMN;       // 91 x 2048

  const size_t needed = 5 * NN * 4
                        + (64 * 64 + 2 * (size_t)DIMN * 64 + 4 * (size_t)DIMN) * 8
                        + (size_t)(2 * RSPLIT) * DIMN * 4;
  if (ws_size < needed) return;

  const float* NUL = nullptr;
  dim3 cb(256), cg(2048);

  unsigned short* Ah  = (unsigned short*)t4;   unsigned short* Al  = Ah + NN;
  unsigned short* Ath = (unsigned short*)Ebuf; unsigned short* Atl = Ath + NN;
  unsigned short* Y2h = (unsigned short*)t1;   unsigned short* Y2l = Y2h + NN;
  unsigned short* Hth = (unsigned short*)t2;   unsigned short* Htl = Hth + NN;

  // ---- Phase 0: bf16 splits of A; Y2 = 0.8281*(A*A) via bf16x3 MFMA; E elementwise ----
  k_split<<<dim3(4096), cb, 0, stream>>>(dA, Ah, Al);
  k_splitT<<<dim3(64, 64), dim3(32, 8), 0, stream>>>(dA, Ath, Atl);
  k_gemm3<<<dim3(16, 16), cb, 0, stream>>>(Ah, Al, Ath, Atl, t3, 0.8281f,
                                           NUL, 0.f, NUL, 0.f);                 // Y2
  k_combine4<<<cg, cb, 0, stream>>>(Ebuf, t3, (float)(5e-5 / 0.8281), dA, 0.01f,
                                    NUL, 0, NUL, 0, 0.f);                       // E

  // ---- Phase 1: M64 = A + 1e-3 I; flat blocked GJ inversion in place (f64) ----
  k_fill64<<<cg, cb, 0, stream>>>(dA, M64);
  for (int p = 0; p < NBLK; ++p) {
    double* Mrow = M64 + (size_t)p * 64 * DIMN;
    k_gj64<<<dim3(1), cb, 0, stream>>>(Mrow + p * 64, DIMN, Dinv, 64);
    k_stagefix<<<dim3(544), cb, 0, stream>>>(Dinv, M64, Rpan, Cpan, p);
    k_dgemm<<<dim3(32, 32), cb, 0, stream>>>(Cpan, 64, Rpan, DIMN, M64, DIMN, 64, -1.0,
                                             M64, DIMN, 1.0);
  }

  // ---- Phase 3: Bbar: y = E*(0.01B); x = W*y; 1x f64 IR ----
  k_vecinit<<<dim3(8), cb, 0, stream>>>(dB, b64, dC, Uc);
  k_mv<<<dim3(512), cb, 0, stream>>>(Ebuf, b64, y64, (const double*)nullptr, 1.0);
  k_mv64<<<dim3(512), cb, 0, stream>>>(M64, y64, x64, (const double*)nullptr, 1.0);
  k_mvres<<<dim3(512), cb, 0, stream>>>(dA, x64, y64, r64);
  k_mv64<<<dim3(512), cb, 0, stream>>>(M64, r64, x64, x64, 1.0);
  k_v0<<<dim3(8), cb, 0, stream>>>(x64, V);                                     // V[0] = Bbar

  // ---- Phase 4: ER = Y2*H + Y2/2 + 0.91A (deg-4 PS), H = (0.91/6)A + Y2/24 ----
  k_combine4<<<cg, cb, 0, stream>>>(t4, dA, 0.91f / 6.f, t3, 1.f / 24.f,
                                    NUL, 0, NUL, 0, 0.f);                       // H -> t4
  k_split<<<dim3(4096), cb, 0, stream>>>(t3, Y2h, Y2l);
  k_splitT<<<dim3(64, 64), dim3(32, 8), 0, stream>>>(t4, Hth, Htl);
  k_gemm3<<<dim3(16, 16), cb, 0, stream>>>(Y2h, Y2l, Hth, Htl, t3, 1.f,
                                           t3, 0.5f, dA, 0.91f);                // ER in-place
  k_transpose<<<dim3(64, 64), dim3(32, 8), 0, stream>>>(t3, t4);                // ERT -> t4

  // ---- Phase 5: balanced serial chains (90 steps) + terms ----
  for (int s = 0; s < NSTEPS; ++s) {
    k_chain<<<dim3(1024), cb, 0, stream>>>(Ebuf, V + (size_t)s * DIMN, V + (size_t)(s + 1) * DIMN,
                                           t4, Uc + (size_t)s * DIMN, Uc + (size_t)(s + 1) * DIMN);
  }
  k_terms<<<dim3(2048), cb, 0, stream>>>(Uc, V, out);
}